// Round 1
// baseline (1943.479 us; speedup 1.0000x reference)
//
#include <hip/hip_runtime.h>

#define BATCH 32
#define NPTS  1024
#define NTOT  (BATCH * NPTS)   // 32768 points

// ---------- helpers ----------

__device__ __forceinline__ float fast_tanh(float x) {
  float ax = fabsf(x);
  float e  = __expf(-2.0f * ax);
  float t  = (1.0f - e) / (1.0f + e);
  return x < 0.0f ? -t : t;
}

// Jacobi polys for a=b=1, degree 3
__device__ __forceinline__ void jacobi4(float t, float& p0, float& p1, float& p2, float& p3) {
  p0 = 1.0f;
  p1 = 2.0f * t;
  p2 = 1.875f * t * p1 - 0.75f;
  p3 = (56.0f / 30.0f) * t * p2 - 0.8f * p1;
}

// monotone float<->uint encoding for atomicMax over signed floats
__device__ __forceinline__ unsigned encf(float f) {
  unsigned b = __float_as_uint(f);
  return b ^ ((unsigned)((int)b >> 31) | 0x80000000u);
}
__device__ __forceinline__ float decf(unsigned u) {
  unsigned b = (u & 0x80000000u) ? (u ^ 0x80000000u) : ~u;
  return __uint_as_float(b);
}

// ---------- zero workspace accumulators ----------
__global__ void zero_ws(unsigned* __restrict__ p, int n) {
  int i = blockIdx.x * 256 + threadIdx.x;
  if (i < n) p[i] = 0u;
}

// ---------- main KAN layer: y[b,o,n] = sum_{i,d} P_d(tanh(norm(in[b,i,n]))) * w[i,o,d] ----------
// 64-point x 64-outchannel tile, 256 threads, K-chunk = 8 channels (K=32).
// If out==nullptr: layer-5 mode -> fused per-channel sum/sumsq (atomicAdd) and per-(b,c) max (atomicMax).
__global__ __launch_bounds__(256, 2) void kan_gemm(
    const float*  __restrict__ in,      // (B, C_in, N)
    const float2* __restrict__ stats,   // per-in-channel (mean, rstd) or nullptr
    const float*  __restrict__ w,       // (C_in, C_out, 4)
    const float*  __restrict__ bias,    // (B, C_out) or nullptr
    float*        __restrict__ out,     // (B, C_out, N) or nullptr
    float*        __restrict__ stat_acc,// (2*C_out) sums if out==nullptr
    unsigned*     __restrict__ max_acc, // (B*C_out) encoded max if out==nullptr
    int C_in, int C_out)
{
  __shared__ __align__(16) float As[32][64];
  __shared__ __align__(16) float Bs[32][64];
  const int t  = threadIdx.x;
  const int mt = blockIdx.x;
  const int b  = mt >> 4;            // 16 tiles of 64 points per batch
  const int n0 = (mt & 15) << 6;
  const int o0 = blockIdx.y << 6;
  const int tm = t & 15;             // point group  (4 points)
  const int to = t >> 4;             // channel group (4 channels)

  float acc[4][4];                   // [oj][mj]
#pragma unroll
  for (int i = 0; i < 4; ++i)
#pragma unroll
    for (int j = 0; j < 4; ++j) acc[i][j] = 0.0f;

  const int nch = (C_in + 7) >> 3;
  for (int ch = 0; ch < nch; ++ch) {
    const int i0 = ch << 3;
    // stage A tile: polys of normalized tanh
#pragma unroll
    for (int r = 0; r < 2; ++r) {
      int e  = t + (r << 8);
      int il = e >> 6, n = e & 63;
      int i  = i0 + il;
      float p0 = 0.f, p1 = 0.f, p2 = 0.f, p3 = 0.f;
      if (i < C_in) {
        float v = in[((b * C_in + i) << 10) + n0 + n];
        if (stats) { float2 s = stats[i]; v = (v - s.x) * s.y; }
        float tt = fast_tanh(v);
        jacobi4(tt, p0, p1, p2, p3);
      }
      As[(il << 2) + 0][n] = p0;
      As[(il << 2) + 1][n] = p1;
      As[(il << 2) + 2][n] = p2;
      As[(il << 2) + 3][n] = p3;
    }
    // stage B tile: weights, float4 per (i, o)
#pragma unroll
    for (int r = 0; r < 2; ++r) {
      int e  = t + (r << 8);
      int il = e >> 6, o = e & 63;
      int i  = i0 + il;
      float4 wv = make_float4(0.f, 0.f, 0.f, 0.f);
      if (i < C_in) wv = *(const float4*)(w + (((i * C_out) + o0 + o) << 2));
      Bs[(il << 2) + 0][o] = wv.x;
      Bs[(il << 2) + 1][o] = wv.y;
      Bs[(il << 2) + 2][o] = wv.z;
      Bs[(il << 2) + 3][o] = wv.w;
    }
    __syncthreads();
#pragma unroll
    for (int k = 0; k < 32; ++k) {
      const float4 a4 = *(const float4*)&As[k][tm << 2];
      const float4 b4 = *(const float4*)&Bs[k][to << 2];
      const float am[4] = {a4.x, a4.y, a4.z, a4.w};
      const float bo[4] = {b4.x, b4.y, b4.z, b4.w};
#pragma unroll
      for (int oj = 0; oj < 4; ++oj)
#pragma unroll
        for (int mj = 0; mj < 4; ++mj)
          acc[oj][mj] = fmaf(bo[oj], am[mj], acc[oj][mj]);
    }
    __syncthreads();
  }

  if (out) {
#pragma unroll
    for (int oj = 0; oj < 4; ++oj) {
      int o = o0 + (to << 2) + oj;
      float bb = bias ? bias[b * C_out + o] : 0.0f;
      float4 v = make_float4(acc[oj][0] + bb, acc[oj][1] + bb,
                             acc[oj][2] + bb, acc[oj][3] + bb);
      *(float4*)(out + ((b * C_out + o) << 10) + n0 + (tm << 2)) = v;
    }
  } else {
    // layer-5 mode: reduce sum/sumsq/max over the 64 points of this tile
#pragma unroll
    for (int oj = 0; oj < 4; ++oj) {
      float s = 0.f, s2 = 0.f, mx = -3.4e38f;
#pragma unroll
      for (int mj = 0; mj < 4; ++mj) {
        float v = acc[oj][mj];
        s += v; s2 += v * v; mx = fmaxf(mx, v);
      }
#pragma unroll
      for (int off = 8; off > 0; off >>= 1) {
        s  += __shfl_down(s, off, 16);
        s2 += __shfl_down(s2, off, 16);
        mx  = fmaxf(mx, __shfl_down(mx, off, 16));
      }
      if (tm == 0) {
        int o = o0 + (to << 2) + oj;
        atomicAdd(&stat_acc[o], s);
        atomicAdd(&stat_acc[C_out + o], s2);
        atomicMax(&max_acc[b * C_out + o], encf(mx));
      }
    }
  }
}

// ---------- BN stats: one block per channel ----------
__global__ __launch_bounds__(256) void bn_stats(
    const float* __restrict__ y, float2* __restrict__ stats, int C)
{
  int c = blockIdx.x;
  float s = 0.f, s2 = 0.f;
  for (int e = threadIdx.x; e < NTOT; e += 256) {
    int b = e >> 10, n = e & 1023;
    float v = y[((b * C + c) << 10) + n];
    s += v; s2 += v * v;
  }
#pragma unroll
  for (int off = 32; off > 0; off >>= 1) {
    s  += __shfl_down(s, off);
    s2 += __shfl_down(s2, off);
  }
  __shared__ float rs[4], rs2[4];
  int wid = threadIdx.x >> 6;
  if ((threadIdx.x & 63) == 0) { rs[wid] = s; rs2[wid] = s2; }
  __syncthreads();
  if (threadIdx.x == 0) {
    s  = rs[0] + rs[1] + rs[2] + rs[3];
    s2 = rs2[0] + rs2[1] + rs2[2] + rs2[3];
    float m   = s * (1.0f / NTOT);
    float var = s2 * (1.0f / NTOT) - m * m;
    stats[c] = make_float2(m, rsqrtf(var + 1e-5f));
  }
}

// ---------- finalize layer-5 stats from atomic accumulators ----------
__global__ void bn_finalize(const float* __restrict__ stat_acc,
                            float2* __restrict__ stats, int C) {
  int c = blockIdx.x * 256 + threadIdx.x;
  if (c < C) {
    float m   = stat_acc[c] * (1.0f / NTOT);
    float var = stat_acc[C + c] * (1.0f / NTOT) - m * m;
    stats[c] = make_float2(m, rsqrtf(var + 1e-5f));
  }
}

// ---------- global-feature branch of layer 6: const6[b,o] = sum_{c,d} P_d(gf_n[b,c]) * w6[64+c,o,d] ----------
__global__ __launch_bounds__(256) void pool_const6(
    const unsigned* __restrict__ max_acc, const float2* __restrict__ stats5,
    const float* __restrict__ w6, float* __restrict__ cst)
{
  __shared__ __align__(16) float4 P[1024];
  int b = blockIdx.x;
  for (int c = threadIdx.x; c < 1024; c += 256) {
    float mx = decf(max_acc[(b << 10) + c]);
    float2 s = stats5[c];
    float tt = fast_tanh((mx - s.x) * s.y);
    float p0, p1, p2, p3; jacobi4(tt, p0, p1, p2, p3);
    P[c] = make_float4(p0, p1, p2, p3);
  }
  __syncthreads();
  for (int o = threadIdx.x; o < 512; o += 256) {
    float a = 0.f;
    for (int c = 0; c < 1024; ++c) {
      float4 wv = *(const float4*)(w6 + (((64 + c) * 512 + o) << 2));
      float4 p  = P[c];
      a += p.x * wv.x + p.y * wv.y + p.z * wv.z + p.w * wv.w;
    }
    cst[(b << 9) + o] = a;
  }
}

// ---------- final layer: C_in=128 -> C_out=3, no BN on output ----------
__global__ __launch_bounds__(256) void kan_final(
    const float* __restrict__ in, const float2* __restrict__ stats,
    const float* __restrict__ w, float* __restrict__ out)
{
  int g = blockIdx.x * 256 + threadIdx.x;
  int b = g >> 10, n = g & 1023;
  float a0 = 0.f, a1 = 0.f, a2 = 0.f;
  for (int i = 0; i < 128; ++i) {
    float v = in[((b * 128 + i) << 10) + n];
    float2 s = stats[i];
    float tt = fast_tanh((v - s.x) * s.y);
    float p0, p1, p2, p3; jacobi4(tt, p0, p1, p2, p3);
    const float4 w0 = *(const float4*)(w + ((i * 3 + 0) << 2));
    const float4 w1 = *(const float4*)(w + ((i * 3 + 1) << 2));
    const float4 w2 = *(const float4*)(w + ((i * 3 + 2) << 2));
    a0 += p0 * w0.x + p1 * w0.y + p2 * w0.z + p3 * w0.w;
    a1 += p0 * w1.x + p1 * w1.y + p2 * w1.z + p3 * w1.w;
    a2 += p0 * w2.x + p1 * w2.y + p2 * w2.z + p3 * w2.w;
  }
  out[((b * 3 + 0) << 10) + n] = a0;
  out[((b * 3 + 1) << 10) + n] = a1;
  out[((b * 3 + 2) << 10) + n] = a2;
}

// ---------- launch ----------
extern "C" void kernel_launch(void* const* d_in, const int* in_sizes, int n_in,
                              void* d_out, int out_size, void* d_ws, size_t ws_size,
                              hipStream_t stream) {
  const float* x   = (const float*)d_in[0];
  const float* w1  = (const float*)d_in[1];
  const float* w2  = (const float*)d_in[2];
  const float* w3  = (const float*)d_in[3];
  const float* w4  = (const float*)d_in[4];
  const float* w5  = (const float*)d_in[5];
  const float* w6  = (const float*)d_in[6];
  const float* w7  = (const float*)d_in[7];
  const float* w8  = (const float*)d_in[8];
  const float* w9  = (const float*)d_in[9];
  const float* w10 = (const float*)d_in[10];

  float* ws = (float*)d_ws;
  // workspace layout (floats)
  float*    stat_acc = ws + 0;                      // 2048
  unsigned* maxenc   = (unsigned*)(ws + 2048);      // 32768 words
  float2*   stats1   = (float2*)(ws + 36864);       // 64 float2
  float2*   stats2   = stats1 + 64;
  float2*   stats3   = stats2 + 64;
  float2*   stats4   = stats3 + 64;                 // 128
  float2*   stats5   = stats4 + 128;                // 1024
  float2*   stats6   = stats5 + 1024;               // 512
  float2*   stats7   = stats6 + 512;                // 256
  float2*   stats8   = stats7 + 256;                // 128
  float2*   stats9   = stats8 + 128;                // 128
  float*    cst6     = ws + 45056;                  // 16384 (32 x 512)
  float*    A0       = ws + 65536;                  // 4M floats (y1, y3, y8)
  float*    A1       = A0 + 4194304;                // 4M (y4, y9)
  float*    A2       = A1 + 4194304;                // 2M (y2, kept for layer 6)
  float*    A3       = A2 + 2097152;                // 16M (y6)
  float*    A4       = A3 + 16777216;               // 8M (y7)
  // total: ~136 MB

  dim3 blk(256);
  zero_ws<<<(34816 + 255) / 256, blk, 0, stream>>>((unsigned*)ws, 34816);

  // L1: 2 -> 64 (input x, no BN on input)
  kan_gemm<<<dim3(512, 1), blk, 0, stream>>>(x, nullptr, w1, nullptr, A0, nullptr, nullptr, 2, 64);
  bn_stats<<<64, blk, 0, stream>>>(A0, stats1, 64);
  // L2: 64 -> 64 (local feature, kept)
  kan_gemm<<<dim3(512, 1), blk, 0, stream>>>(A0, stats1, w2, nullptr, A2, nullptr, nullptr, 64, 64);
  bn_stats<<<64, blk, 0, stream>>>(A2, stats2, 64);
  // L3: 64 -> 64
  kan_gemm<<<dim3(512, 1), blk, 0, stream>>>(A2, stats2, w3, nullptr, A0, nullptr, nullptr, 64, 64);
  bn_stats<<<64, blk, 0, stream>>>(A0, stats3, 64);
  // L4: 64 -> 128
  kan_gemm<<<dim3(512, 2), blk, 0, stream>>>(A0, stats3, w4, nullptr, A1, nullptr, nullptr, 64, 128);
  bn_stats<<<128, blk, 0, stream>>>(A1, stats4, 128);
  // L5: 128 -> 1024, fused stats + maxpool, no output materialization
  kan_gemm<<<dim3(512, 16), blk, 0, stream>>>(A1, stats4, w5, nullptr, nullptr, stat_acc, maxenc, 128, 1024);
  bn_finalize<<<4, blk, 0, stream>>>(stat_acc, stats5, 1024);
  // global-feature contribution to layer 6 (constant over n)
  pool_const6<<<32, blk, 0, stream>>>(maxenc, stats5, w6, cst6);
  // L6: 64 (local) -> 512, + per-(b,o) bias from gf branch
  kan_gemm<<<dim3(512, 8), blk, 0, stream>>>(A2, stats2, w6, cst6, A3, nullptr, nullptr, 64, 512);
  bn_stats<<<512, blk, 0, stream>>>(A3, stats6, 512);
  // L7: 512 -> 256
  kan_gemm<<<dim3(512, 4), blk, 0, stream>>>(A3, stats6, w7, nullptr, A4, nullptr, nullptr, 512, 256);
  bn_stats<<<256, blk, 0, stream>>>(A4, stats7, 256);
  // L8: 256 -> 128
  kan_gemm<<<dim3(512, 2), blk, 0, stream>>>(A4, stats7, w8, nullptr, A0, nullptr, nullptr, 256, 128);
  bn_stats<<<128, blk, 0, stream>>>(A0, stats8, 128);
  // L9: 128 -> 128
  kan_gemm<<<dim3(512, 2), blk, 0, stream>>>(A0, stats8, w9, nullptr, A1, nullptr, nullptr, 128, 128);
  bn_stats<<<128, blk, 0, stream>>>(A1, stats9, 128);
  // L10: 128 -> 3
  kan_final<<<128, blk, 0, stream>>>(A1, stats9, w10, (float*)d_out);
}

// Round 2
// 1711.651 us; speedup vs baseline: 1.1354x; 1.1354x over previous
//
#include <hip/hip_runtime.h>

#define BATCH 32
#define NPTS  1024
#define NTOT  (BATCH * NPTS)   // 32768 points

// ---------- helpers ----------

__device__ __forceinline__ float fast_tanh(float x) {
  float ax = fabsf(x);
  float e  = __expf(-2.0f * ax);
  float t  = (1.0f - e) / (1.0f + e);
  return x < 0.0f ? -t : t;
}

// Jacobi polys for a=b=1, degree 3
__device__ __forceinline__ void jacobi4(float t, float& p0, float& p1, float& p2, float& p3) {
  p0 = 1.0f;
  p1 = 2.0f * t;
  p2 = 1.875f * t * p1 - 0.75f;
  p3 = (56.0f / 30.0f) * t * p2 - 0.8f * p1;
}

// monotone float<->uint encoding for atomicMax over signed floats
__device__ __forceinline__ unsigned encf(float f) {
  unsigned b = __float_as_uint(f);
  return b ^ ((unsigned)((int)b >> 31) | 0x80000000u);
}
__device__ __forceinline__ float decf(unsigned u) {
  unsigned b = (u & 0x80000000u) ? (u ^ 0x80000000u) : ~u;
  return __uint_as_float(b);
}

// ---------- zero workspace accumulators ----------
__global__ void zero_ws(unsigned* __restrict__ p, int n) {
  int i = blockIdx.x * 256 + threadIdx.x;
  if (i < n) p[i] = 0u;
}

// ---------- main KAN layer: y[b,o,n] = sum_{i,d} P_d(tanh(norm(in[b,i,n]))) * w[i,o,d] ----------
// BM points x BN outs per block, 256 threads, 8x8 per thread (split-quad fragments),
// K-chunk = 8 in-channels (K=32). Fused BN-stats epilogue:
//   out != nullptr : write y, write per-(o, xblock) partial (sum,sumsq) to spart
//   out == nullptr : layer-5 mode -> atomicAdd stats into stat_acc + per-(b,o) atomicMax
template<int BM, int BN>
__global__ __launch_bounds__(256) void kan_gemm(
    const float*  __restrict__ in,      // (B, C_in, N)
    const float2* __restrict__ stats,   // per-in-channel (mean, rstd) or nullptr
    const float*  __restrict__ w,       // (C_in, C_out, 4)
    const float*  __restrict__ bias,    // (B, C_out) or nullptr
    float*        __restrict__ out,     // (B, C_out, N) or nullptr
    float2*       __restrict__ spart,   // (C_out, 256) partial (sum,sumsq)
    float*        __restrict__ stat_acc,// (2*C_out) atomic sums (L5 mode)
    unsigned*     __restrict__ max_acc, // (B*C_out) encoded max (L5 mode)
    int C_in, int C_out)
{
  constexpr int TM = BM / 8;           // tm groups (16 or 32)
  constexpr int AE = 8 * BM / 256;     // raw A elems per thread per chunk
  constexpr int BE = 8 * BN / 256;
  __shared__ __align__(16) float As[32][BM];
  __shared__ __align__(16) float Bs[32][BN];

  const int t  = threadIdx.x;
  const int tpb = NPTS / BM;                   // point-tiles per batch
  const int b  = blockIdx.x / tpb;
  const int n0 = (blockIdx.x % tpb) * BM;
  const int o0 = blockIdx.y * BN;
  const int tm = t % TM;
  const int to = t / TM;

  float acc[2][4][2][4];               // [oh][oj][mh][mj]
#pragma unroll
  for (int a = 0; a < 2; ++a)
#pragma unroll
    for (int c = 0; c < 4; ++c)
#pragma unroll
      for (int d = 0; d < 2; ++d)
#pragma unroll
        for (int e = 0; e < 4; ++e) acc[a][c][d][e] = 0.0f;

  const int nch = (C_in + 7) >> 3;
  for (int ch = 0; ch < nch; ++ch) {
    const int i0 = ch << 3;
    __syncthreads();
    // stage A tile: polys of normalized tanh
#pragma unroll
    for (int r = 0; r < AE; ++r) {
      int e  = t + (r << 8);
      int il = e / BM, n = e % BM;
      int i  = i0 + il;
      float p0 = 0.f, p1 = 0.f, p2 = 0.f, p3 = 0.f;
      if (i < C_in) {
        float v = in[((size_t)(b * C_in + i) << 10) + n0 + n];
        if (stats) { float2 s = stats[i]; v = (v - s.x) * s.y; }
        float tt = fast_tanh(v);
        jacobi4(tt, p0, p1, p2, p3);
      }
      As[(il << 2) + 0][n] = p0;
      As[(il << 2) + 1][n] = p1;
      As[(il << 2) + 2][n] = p2;
      As[(il << 2) + 3][n] = p3;
    }
    // stage B tile: weights, float4 per (i, o)
#pragma unroll
    for (int r = 0; r < BE; ++r) {
      int e  = t + (r << 8);
      int il = e / BN, o = e % BN;
      int i  = i0 + il;
      float4 wv = make_float4(0.f, 0.f, 0.f, 0.f);
      if (i < C_in) wv = *(const float4*)(w + (((size_t)i * C_out + o0 + o) << 2));
      Bs[(il << 2) + 0][o] = wv.x;
      Bs[(il << 2) + 1][o] = wv.y;
      Bs[(il << 2) + 2][o] = wv.z;
      Bs[(il << 2) + 3][o] = wv.w;
    }
    __syncthreads();
#pragma unroll 8
    for (int k = 0; k < 32; ++k) {
      const float4 a0 = *(const float4*)&As[k][tm << 2];
      const float4 a1 = *(const float4*)&As[k][(BM / 2) + (tm << 2)];
      const float4 b0 = *(const float4*)&Bs[k][to << 2];
      const float4 b1 = *(const float4*)&Bs[k][(BN / 2) + (to << 2)];
      const float am[2][4] = {{a0.x, a0.y, a0.z, a0.w}, {a1.x, a1.y, a1.z, a1.w}};
      const float bo[2][4] = {{b0.x, b0.y, b0.z, b0.w}, {b1.x, b1.y, b1.z, b1.w}};
#pragma unroll
      for (int oh = 0; oh < 2; ++oh)
#pragma unroll
        for (int oj = 0; oj < 4; ++oj) {
          const float bv = bo[oh][oj];
#pragma unroll
          for (int mh = 0; mh < 2; ++mh)
#pragma unroll
            for (int mj = 0; mj < 4; ++mj)
              acc[oh][oj][mh][mj] = fmaf(bv, am[mh][mj], acc[oh][oj][mh][mj]);
        }
    }
  }

  // epilogue: bias, output write, fused BN stats
#pragma unroll
  for (int oh = 0; oh < 2; ++oh)
#pragma unroll
    for (int oj = 0; oj < 4; ++oj) {
      const int o = o0 + oh * (BN / 2) + (to << 2) + oj;
      const float bb = bias ? bias[b * C_out + o] : 0.0f;
      float v[2][4];
      float s = 0.f, s2 = 0.f, mx = -3.4e38f;
#pragma unroll
      for (int mh = 0; mh < 2; ++mh)
#pragma unroll
        for (int mj = 0; mj < 4; ++mj) {
          float x = acc[oh][oj][mh][mj] + bb;
          v[mh][mj] = x;
          s += x; s2 += x * x; mx = fmaxf(mx, x);
        }
      if (out) {
#pragma unroll
        for (int mh = 0; mh < 2; ++mh)
          *(float4*)(out + (((size_t)(b * C_out + o)) << 10) + n0 + mh * (BM / 2) + (tm << 2)) =
              make_float4(v[mh][0], v[mh][1], v[mh][2], v[mh][3]);
      }
#pragma unroll
      for (int off = TM / 2; off > 0; off >>= 1) {
        s  += __shfl_down(s, off, TM);
        s2 += __shfl_down(s2, off, TM);
        mx  = fmaxf(mx, __shfl_down(mx, off, TM));
      }
      if (tm == 0) {
        if (out) {
          spart[(o << 8) + blockIdx.x] = make_float2(s, s2);
        } else {
          atomicAdd(&stat_acc[o], s);
          atomicAdd(&stat_acc[C_out + o], s2);
          atomicMax(&max_acc[b * C_out + o], encf(mx));
        }
      }
    }
}

// ---------- reduce per-block partials -> BN stats ----------
__global__ __launch_bounds__(256) void bn_finalize2(
    const float2* __restrict__ spart, float2* __restrict__ stats, int C, int nxb)
{
  int c = blockIdx.x, t = threadIdx.x;
  float s = 0.f, s2 = 0.f;
  if (t < nxb) { float2 p = spart[(c << 8) + t]; s = p.x; s2 = p.y; }
#pragma unroll
  for (int off = 32; off > 0; off >>= 1) {
    s  += __shfl_down(s, off);
    s2 += __shfl_down(s2, off);
  }
  __shared__ float rs[4], rs2[4];
  int wid = t >> 6;
  if ((t & 63) == 0) { rs[wid] = s; rs2[wid] = s2; }
  __syncthreads();
  if (t == 0) {
    s  = rs[0] + rs[1] + rs[2] + rs[3];
    s2 = rs2[0] + rs2[1] + rs2[2] + rs2[3];
    float m   = s * (1.0f / NTOT);
    float var = s2 * (1.0f / NTOT) - m * m;
    stats[c] = make_float2(m, rsqrtf(var + 1e-5f));
  }
}

// ---------- finalize layer-5 stats from atomic accumulators ----------
__global__ void bn_finalize(const float* __restrict__ stat_acc,
                            float2* __restrict__ stats, int C) {
  int c = blockIdx.x * 256 + threadIdx.x;
  if (c < C) {
    float m   = stat_acc[c] * (1.0f / NTOT);
    float var = stat_acc[C + c] * (1.0f / NTOT) - m * m;
    stats[c] = make_float2(m, rsqrtf(var + 1e-5f));
  }
}

// ---------- global-feature branch of layer 6: const6[b,o] = sum_{c,d} P_d(gf_n[b,c]) * w6[64+c,o,d] ----------
__global__ __launch_bounds__(256) void pool_const6(
    const unsigned* __restrict__ max_acc, const float2* __restrict__ stats5,
    const float* __restrict__ w6, float* __restrict__ cst)
{
  __shared__ __align__(16) float4 P[1024];
  int b = blockIdx.x;
  for (int c = threadIdx.x; c < 1024; c += 256) {
    float mx = decf(max_acc[(b << 10) + c]);
    float2 s = stats5[c];
    float tt = fast_tanh((mx - s.x) * s.y);
    float p0, p1, p2, p3; jacobi4(tt, p0, p1, p2, p3);
    P[c] = make_float4(p0, p1, p2, p3);
  }
  __syncthreads();
  for (int o = threadIdx.x; o < 512; o += 256) {
    float a = 0.f;
    for (int c = 0; c < 1024; ++c) {
      float4 wv = *(const float4*)(w6 + (((size_t)(64 + c) * 512 + o) << 2));
      float4 p  = P[c];
      a += p.x * wv.x + p.y * wv.y + p.z * wv.z + p.w * wv.w;
    }
    cst[(b << 9) + o] = a;
  }
}

// ---------- final layer: C_in=128 -> C_out=3, no BN on output ----------
__global__ __launch_bounds__(256) void kan_final(
    const float* __restrict__ in, const float2* __restrict__ stats,
    const float* __restrict__ w, float* __restrict__ out)
{
  int g = blockIdx.x * 256 + threadIdx.x;
  int b = g >> 10, n = g & 1023;
  float a0 = 0.f, a1 = 0.f, a2 = 0.f;
  for (int i = 0; i < 128; ++i) {
    float v = in[((size_t)(b * 128 + i) << 10) + n];
    float2 s = stats[i];
    float tt = fast_tanh((v - s.x) * s.y);
    float p0, p1, p2, p3; jacobi4(tt, p0, p1, p2, p3);
    const float4 w0 = *(const float4*)(w + ((i * 3 + 0) << 2));
    const float4 w1 = *(const float4*)(w + ((i * 3 + 1) << 2));
    const float4 w2 = *(const float4*)(w + ((i * 3 + 2) << 2));
    a0 += p0 * w0.x + p1 * w0.y + p2 * w0.z + p3 * w0.w;
    a1 += p0 * w1.x + p1 * w1.y + p2 * w1.z + p3 * w1.w;
    a2 += p0 * w2.x + p1 * w2.y + p2 * w2.z + p3 * w2.w;
  }
  out[((b * 3 + 0) << 10) + n] = a0;
  out[((b * 3 + 1) << 10) + n] = a1;
  out[((b * 3 + 2) << 10) + n] = a2;
}

// ---------- launch ----------
extern "C" void kernel_launch(void* const* d_in, const int* in_sizes, int n_in,
                              void* d_out, int out_size, void* d_ws, size_t ws_size,
                              hipStream_t stream) {
  const float* x   = (const float*)d_in[0];
  const float* w1  = (const float*)d_in[1];
  const float* w2  = (const float*)d_in[2];
  const float* w3  = (const float*)d_in[3];
  const float* w4  = (const float*)d_in[4];
  const float* w5  = (const float*)d_in[5];
  const float* w6  = (const float*)d_in[6];
  const float* w7  = (const float*)d_in[7];
  const float* w8  = (const float*)d_in[8];
  const float* w9  = (const float*)d_in[9];
  const float* w10 = (const float*)d_in[10];

  float* ws = (float*)d_ws;
  // workspace layout (floats)
  float*    stat_acc = ws + 0;                      // 2048
  unsigned* maxenc   = (unsigned*)(ws + 2048);      // 32768 words
  float2*   spart    = (float2*)(ws + 34816);       // 131072 float2 (512 ch x 256 blk)
  float2*   stats1   = (float2*)(ws + 296960);      // 64
  float2*   stats2   = stats1 + 64;
  float2*   stats3   = stats2 + 64;
  float2*   stats4   = stats3 + 64;                 // 128
  float2*   stats5   = stats4 + 128;                // 1024
  float2*   stats6   = stats5 + 1024;               // 512
  float2*   stats7   = stats6 + 512;                // 256
  float2*   stats8   = stats7 + 256;                // 128
  float2*   stats9   = stats8 + 128;                // 128
  float*    cst6     = ws + 301696;                 // 16384 (32 x 512)
  float*    A0       = ws + 327680;                 // 2M floats (y1, y3)
  float*    A1       = A0 + 2097152;                // 4M (y4, y9)
  float*    A2       = A1 + 4194304;                // 2M (y2, kept for layer 6)
  float*    A3       = A2 + 2097152;                // 16M (y6, then y8)
  float*    A4       = A3 + 16777216;               // 8M (y7)
  // total: ~135.5 MB (< R0's proven 142.9 MB footprint)

  dim3 blk(256);
  zero_ws<<<136, blk, 0, stream>>>((unsigned*)ws, 34816);

  // L1: 2 -> 64 (input x, no BN on input)
  kan_gemm<256, 64><<<dim3(128, 1), blk, 0, stream>>>(x, nullptr, w1, nullptr, A0, spart, nullptr, nullptr, 2, 64);
  bn_finalize2<<<64, blk, 0, stream>>>(spart, stats1, 64, 128);
  // L2: 64 -> 64 (local feature, kept)
  kan_gemm<256, 64><<<dim3(128, 1), blk, 0, stream>>>(A0, stats1, w2, nullptr, A2, spart, nullptr, nullptr, 64, 64);
  bn_finalize2<<<64, blk, 0, stream>>>(spart, stats2, 64, 128);
  // L3: 64 -> 64
  kan_gemm<256, 64><<<dim3(128, 1), blk, 0, stream>>>(A2, stats2, w3, nullptr, A0, spart, nullptr, nullptr, 64, 64);
  bn_finalize2<<<64, blk, 0, stream>>>(spart, stats3, 64, 128);
  // L4: 64 -> 128
  kan_gemm<128, 128><<<dim3(256, 1), blk, 0, stream>>>(A0, stats3, w4, nullptr, A1, spart, nullptr, nullptr, 64, 128);
  bn_finalize2<<<128, blk, 0, stream>>>(spart, stats4, 128, 256);
  // L5: 128 -> 1024, fused stats + maxpool, no output materialization
  kan_gemm<128, 128><<<dim3(256, 8), blk, 0, stream>>>(A1, stats4, w5, nullptr, nullptr, nullptr, stat_acc, maxenc, 128, 1024);
  bn_finalize<<<4, blk, 0, stream>>>(stat_acc, stats5, 1024);
  // global-feature contribution to layer 6 (constant over n)
  pool_const6<<<32, blk, 0, stream>>>(maxenc, stats5, w6, cst6);
  // L6: 64 (local) -> 512, + per-(b,o) bias from gf branch
  kan_gemm<128, 128><<<dim3(256, 4), blk, 0, stream>>>(A2, stats2, w6, cst6, A3, spart, nullptr, nullptr, 64, 512);
  bn_finalize2<<<512, blk, 0, stream>>>(spart, stats6, 512, 256);
  // L7: 512 -> 256
  kan_gemm<128, 128><<<dim3(256, 2), blk, 0, stream>>>(A3, stats6, w7, nullptr, A4, spart, nullptr, nullptr, 512, 256);
  bn_finalize2<<<256, blk, 0, stream>>>(spart, stats7, 256, 256);
  // L8: 256 -> 128 (y8 reuses y6's region, dead after L7)
  kan_gemm<128, 128><<<dim3(256, 1), blk, 0, stream>>>(A4, stats7, w8, nullptr, A3, spart, nullptr, nullptr, 256, 128);
  bn_finalize2<<<128, blk, 0, stream>>>(spart, stats8, 128, 256);
  // L9: 128 -> 128
  kan_gemm<128, 128><<<dim3(256, 1), blk, 0, stream>>>(A3, stats8, w9, nullptr, A1, spart, nullptr, nullptr, 128, 128);
  bn_finalize2<<<128, blk, 0, stream>>>(spart, stats9, 128, 256);
  // L10: 128 -> 3
  kan_final<<<128, blk, 0, stream>>>(A1, stats9, w10, (float*)d_out);
}

// Round 4
// 846.071 us; speedup vs baseline: 2.2971x; 2.0231x over previous
//
#include <hip/hip_runtime.h>

#define BATCH 32
#define NPTS  1024
#define NTOT  (BATCH * NPTS)   // 32768 points

typedef _Float16 half8 __attribute__((ext_vector_type(8)));
typedef float    f32x4 __attribute__((ext_vector_type(4)));

// ---------- helpers ----------

__device__ __forceinline__ float fast_tanh(float x) {
  float ax = fabsf(x);
  float e  = __expf(-2.0f * ax);
  float t  = (1.0f - e) / (1.0f + e);
  return x < 0.0f ? -t : t;
}

// Jacobi polys for a=b=1, degree 3: p1=2t, p2=3.75t^2-0.75, p3=7t^3-3t
__device__ __forceinline__ void jacobi4(float t, float& p0, float& p1, float& p2, float& p3) {
  float t2 = t * t;
  p0 = 1.0f;
  p1 = 2.0f * t;
  p2 = 3.75f * t2 - 0.75f;
  p3 = t * (7.0f * t2 - 3.0f);
}

// monotone float<->uint encoding for atomicMax over signed floats
__device__ __forceinline__ unsigned encf(float f) {
  unsigned b = __float_as_uint(f);
  return b ^ ((unsigned)((int)b >> 31) | 0x80000000u);
}
__device__ __forceinline__ float decf(unsigned u) {
  unsigned b = (u & 0x80000000u) ? (u ^ 0x80000000u) : ~u;
  return __uint_as_float(b);
}

// ---------- zero workspace accumulators ----------
__global__ void zero_ws(unsigned* __restrict__ p, int n) {
  int i = blockIdx.x * 256 + threadIdx.x;
  if (i < n) p[i] = 0u;
}

// ---------- MFMA KAN layer (fp16 inputs, fp32 accumulate) ----------
// Requirements: C_in % 16 == 0, C_out % 128 == 0.
// Block tile: 128 points x 128 out-channels, 256 threads (4 waves, 2x2 wave grid
// of 64x64 wave tiles, each 4x4 fragments of mfma_f32_16x16x32_f16).
// K-chunk = 64 (16 in-channels x 4 degrees). LDS in fragment-ready 16B slots.
// A/B staged identically ([k-slot][elem]) so any HW k-relabeling cancels.
// Verified layouts: A m=lane&15, k=quad*8+j; C/D row(M)=quad*4+reg, col(N)=lane&15.
// Weights scaled x64 at staging (undone in epilogue) to avoid fp16 subnormals.
// Epilogue:
//   out != nullptr : write y + per-(o, xblock) partial (sum,sumsq) to spart
//   out == nullptr : L5 mode -> atomicAdd channel sums + per-(b,o) atomicMax
__global__ __launch_bounds__(256, 2) void kan_mfma(
    const float*  __restrict__ in,      // (B, C_in, N)
    const float2* __restrict__ stats,   // per-in-channel (mean, rstd)
    const float*  __restrict__ w,       // (C_in, C_out, 4)
    const float*  __restrict__ bias,    // (B, C_out) or nullptr
    float*        __restrict__ out,     // (B, C_out, N) or nullptr
    float2*       __restrict__ spart,   // (C_out, 256) partials
    float*        __restrict__ stat_acc,// (2*C_out) atomic sums (L5 mode)
    unsigned*     __restrict__ max_acc, // (B*C_out) encoded max (L5 mode)
    int C_in, int C_out)
{
  __shared__ half8 As[1024];            // [kb:8][m:128]
  __shared__ half8 Bsh[1024];           // [kb:8][o:128]
  __shared__ float sredS[128][2], sredS2[128][2], sredM[128][2];

  const int t    = threadIdx.x;
  const int lane = t & 63;
  const int col  = lane & 15;
  const int quad = lane >> 4;
  const int wv   = t >> 6;
  const int wm   = wv & 1;              // m-half of block
  const int wn   = wv >> 1;             // n-half of block
  const int b    = blockIdx.x >> 3;     // 8 point-tiles of 128 per batch
  const int n0   = (blockIdx.x & 7) << 7;
  const int o0   = blockIdx.y << 7;

  f32x4 acc[4][4];
#pragma unroll
  for (int i = 0; i < 4; ++i)
#pragma unroll
    for (int j = 0; j < 4; ++j)
#pragma unroll
      for (int k = 0; k < 4; ++k) acc[i][j][k] = 0.0f;

  const int nch = C_in >> 4;
  for (int ch = 0; ch < nch; ++ch) {
    const int i0 = ch << 4;
    __syncthreads();
    // ---- stage A: polys of tanh(norm(in)), 4 slots/thread ----
#pragma unroll
    for (int r = 0; r < 4; ++r) {
      int s  = t + (r << 8);
      int kb = s >> 7, m = s & 127;
      int i  = i0 + (kb << 1);
      const float* ip = in + (((size_t)(b * C_in + i)) << 10) + n0 + m;
      float v0 = ip[0], v1 = ip[1024];
      float2 st0 = stats[i], st1 = stats[i + 1];
      v0 = (v0 - st0.x) * st0.y;
      v1 = (v1 - st1.x) * st1.y;
      float t0 = fast_tanh(v0), t1 = fast_tanh(v1);
      float p0, p1, p2, p3, q0, q1, q2, q3;
      jacobi4(t0, p0, p1, p2, p3);
      jacobi4(t1, q0, q1, q2, q3);
      half8 h;
      h[0] = (_Float16)p0; h[1] = (_Float16)p1; h[2] = (_Float16)p2; h[3] = (_Float16)p3;
      h[4] = (_Float16)q0; h[5] = (_Float16)q1; h[6] = (_Float16)q2; h[7] = (_Float16)q3;
      As[(kb << 7) + m] = h;
    }
    // ---- stage B: weights x64, 4 slots/thread ----
#pragma unroll
    for (int r = 0; r < 4; ++r) {
      int s  = t + (r << 8);
      int kb = s >> 7, o = s & 127;
      int i  = i0 + (kb << 1);
      const float4 wa = *(const float4*)(w + (((size_t)i * C_out + o0 + o) << 2));
      const float4 wb = *(const float4*)(w + (((size_t)(i + 1) * C_out + o0 + o) << 2));
      half8 h;
      h[0] = (_Float16)(wa.x * 64.0f); h[1] = (_Float16)(wa.y * 64.0f);
      h[2] = (_Float16)(wa.z * 64.0f); h[3] = (_Float16)(wa.w * 64.0f);
      h[4] = (_Float16)(wb.x * 64.0f); h[5] = (_Float16)(wb.y * 64.0f);
      h[6] = (_Float16)(wb.z * 64.0f); h[7] = (_Float16)(wb.w * 64.0f);
      Bsh[(kb << 7) + o] = h;
    }
    __syncthreads();
    // ---- MFMA: 2 k-steps of 32 ----
#pragma unroll
    for (int ks = 0; ks < 2; ++ks) {
      half8 af[4], bf[4];
#pragma unroll
      for (int f = 0; f < 4; ++f) {
        af[f] = As [(((ks << 2) + quad) << 7) + (wm << 6) + (f << 4) + col];
        bf[f] = Bsh[(((ks << 2) + quad) << 7) + (wn << 6) + (f << 4) + col];
      }
#pragma unroll
      for (int fm = 0; fm < 4; ++fm)
#pragma unroll
        for (int fn = 0; fn < 4; ++fn)
          acc[fm][fn] = __builtin_amdgcn_mfma_f32_16x16x32_f16(af[fm], bf[fn], acc[fm][fn], 0, 0, 0);
    }
  }

  // ---- epilogue: unscale, bias, write, fused BN stats ----
  // C/D layout: n(col)=lane&15, m(row)=quad*4+reg
  const float inv64 = 0.015625f;
#pragma unroll
  for (int fn = 0; fn < 4; ++fn) {
    const int cl = (wn << 6) + (fn << 4) + col;   // block-local out channel
    const int o  = o0 + cl;
    const float bb = bias ? bias[b * C_out + o] : 0.0f;
    float s = 0.f, s2 = 0.f, mx = -3.4e38f;
#pragma unroll
    for (int fm = 0; fm < 4; ++fm) {
      float v0 = acc[fm][fn][0] * inv64 + bb;
      float v1 = acc[fm][fn][1] * inv64 + bb;
      float v2 = acc[fm][fn][2] * inv64 + bb;
      float v3 = acc[fm][fn][3] * inv64 + bb;
      if (out) {
        *(float4*)(out + (((size_t)(b * C_out + o)) << 10) + n0 + (wm << 6) + (fm << 4) + (quad << 2)) =
            make_float4(v0, v1, v2, v3);
      }
      s  += v0 + v1 + v2 + v3;
      s2 += v0 * v0 + v1 * v1 + v2 * v2 + v3 * v3;
      mx  = fmaxf(fmaxf(v0, v1), fmaxf(fmaxf(v2, v3), mx));
    }
    // reduce over the 4 quads (same channel, different point groups)
    s  += __shfl_down(s, 32);  s  += __shfl_down(s, 16);
    s2 += __shfl_down(s2, 32); s2 += __shfl_down(s2, 16);
    mx  = fmaxf(mx, __shfl_down(mx, 32)); mx = fmaxf(mx, __shfl_down(mx, 16));
    if (lane < 16) {
      sredS [cl][wm] = s;
      sredS2[cl][wm] = s2;
      sredM [cl][wm] = mx;
    }
  }
  __syncthreads();
  if (t < 128) {
    const int o = o0 + t;
    float s  = sredS [t][0] + sredS [t][1];
    float s2 = sredS2[t][0] + sredS2[t][1];
    if (out) {
      spart[(o << 8) + blockIdx.x] = make_float2(s, s2);
    } else {
      float mx = fmaxf(sredM[t][0], sredM[t][1]);
      atomicAdd(&stat_acc[o], s);
      atomicAdd(&stat_acc[C_out + o], s2);
      atomicMax(&max_acc[b * C_out + o], encf(mx));
    }
  }
}

// ---------- fp32 KAN layer (small layers L1-L3) ----------
// 256 threads, 8x8 outputs per thread => REQUIRES BM*BN == 16384.
template<int BM, int BN>
__global__ __launch_bounds__(256) void kan_gemm(
    const float*  __restrict__ in, const float2* __restrict__ stats,
    const float*  __restrict__ w, float* __restrict__ out,
    float2* __restrict__ spart, int C_in, int C_out)
{
  static_assert(BM * BN == 256 * 64, "8x8-per-thread tile requires BM*BN == 16384");
  constexpr int TM = BM / 8;
  constexpr int AE = 8 * BM / 256;
  constexpr int BE = 8 * BN / 256;
  __shared__ __align__(16) float As[32][BM];
  __shared__ __align__(16) float Bs[32][BN];

  const int t  = threadIdx.x;
  const int tpb = NPTS / BM;
  const int b  = blockIdx.x / tpb;
  const int n0 = (blockIdx.x % tpb) * BM;
  const int o0 = blockIdx.y * BN;
  const int tm = t % TM;
  const int to = t / TM;

  float acc[2][4][2][4];
#pragma unroll
  for (int a = 0; a < 2; ++a)
#pragma unroll
    for (int c = 0; c < 4; ++c)
#pragma unroll
      for (int d = 0; d < 2; ++d)
#pragma unroll
        for (int e = 0; e < 4; ++e) acc[a][c][d][e] = 0.0f;

  const int nch = (C_in + 7) >> 3;
  for (int ch = 0; ch < nch; ++ch) {
    const int i0 = ch << 3;
    __syncthreads();
#pragma unroll
    for (int r = 0; r < AE; ++r) {
      int e  = t + (r << 8);
      int il = e / BM, n = e % BM;
      int i  = i0 + il;
      float p0 = 0.f, p1 = 0.f, p2 = 0.f, p3 = 0.f;
      if (i < C_in) {
        float v = in[((size_t)(b * C_in + i) << 10) + n0 + n];
        if (stats) { float2 s = stats[i]; v = (v - s.x) * s.y; }
        jacobi4(fast_tanh(v), p0, p1, p2, p3);
      }
      As[(il << 2) + 0][n] = p0;
      As[(il << 2) + 1][n] = p1;
      As[(il << 2) + 2][n] = p2;
      As[(il << 2) + 3][n] = p3;
    }
#pragma unroll
    for (int r = 0; r < BE; ++r) {
      int e  = t + (r << 8);
      int il = e / BN, o = e % BN;
      int i  = i0 + il;
      float4 wv = make_float4(0.f, 0.f, 0.f, 0.f);
      if (i < C_in) wv = *(const float4*)(w + (((size_t)i * C_out + o0 + o) << 2));
      Bs[(il << 2) + 0][o] = wv.x;
      Bs[(il << 2) + 1][o] = wv.y;
      Bs[(il << 2) + 2][o] = wv.z;
      Bs[(il << 2) + 3][o] = wv.w;
    }
    __syncthreads();
#pragma unroll 8
    for (int k = 0; k < 32; ++k) {
      const float4 a0 = *(const float4*)&As[k][tm << 2];
      const float4 a1 = *(const float4*)&As[k][(BM / 2) + (tm << 2)];
      const float4 b0 = *(const float4*)&Bs[k][to << 2];
      const float4 b1 = *(const float4*)&Bs[k][(BN / 2) + (to << 2)];
      const float am[2][4] = {{a0.x, a0.y, a0.z, a0.w}, {a1.x, a1.y, a1.z, a1.w}};
      const float bo[2][4] = {{b0.x, b0.y, b0.z, b0.w}, {b1.x, b1.y, b1.z, b1.w}};
#pragma unroll
      for (int oh = 0; oh < 2; ++oh)
#pragma unroll
        for (int oj = 0; oj < 4; ++oj) {
          const float bv = bo[oh][oj];
#pragma unroll
          for (int mh = 0; mh < 2; ++mh)
#pragma unroll
            for (int mj = 0; mj < 4; ++mj)
              acc[oh][oj][mh][mj] = fmaf(bv, am[mh][mj], acc[oh][oj][mh][mj]);
        }
    }
  }

#pragma unroll
  for (int oh = 0; oh < 2; ++oh)
#pragma unroll
    for (int oj = 0; oj < 4; ++oj) {
      const int o = o0 + oh * (BN / 2) + (to << 2) + oj;
      float s = 0.f, s2 = 0.f;
#pragma unroll
      for (int mh = 0; mh < 2; ++mh) {
        float4 v = make_float4(acc[oh][oj][mh][0], acc[oh][oj][mh][1],
                               acc[oh][oj][mh][2], acc[oh][oj][mh][3]);
        *(float4*)(out + (((size_t)(b * C_out + o)) << 10) + n0 + mh * (BM / 2) + (tm << 2)) = v;
        s  += v.x + v.y + v.z + v.w;
        s2 += v.x * v.x + v.y * v.y + v.z * v.z + v.w * v.w;
      }
#pragma unroll
      for (int off = TM / 2; off > 0; off >>= 1) {
        s  += __shfl_down(s, off, TM);
        s2 += __shfl_down(s2, off, TM);
      }
      if (tm == 0) spart[(o << 8) + blockIdx.x] = make_float2(s, s2);
    }
}

// ---------- reduce per-block partials -> BN stats ----------
__global__ __launch_bounds__(256) void bn_finalize2(
    const float2* __restrict__ spart, float2* __restrict__ stats, int C, int nxb)
{
  int c = blockIdx.x, t = threadIdx.x;
  float s = 0.f, s2 = 0.f;
  if (t < nxb) { float2 p = spart[(c << 8) + t]; s = p.x; s2 = p.y; }
#pragma unroll
  for (int off = 32; off > 0; off >>= 1) {
    s  += __shfl_down(s, off);
    s2 += __shfl_down(s2, off);
  }
  __shared__ float rs[4], rs2[4];
  int wid = t >> 6;
  if ((t & 63) == 0) { rs[wid] = s; rs2[wid] = s2; }
  __syncthreads();
  if (t == 0) {
    s  = rs[0] + rs[1] + rs[2] + rs[3];
    s2 = rs2[0] + rs2[1] + rs2[2] + rs2[3];
    float m   = s * (1.0f / NTOT);
    float var = s2 * (1.0f / NTOT) - m * m;
    stats[c] = make_float2(m, rsqrtf(var + 1e-5f));
  }
}

// ---------- finalize layer-5 stats from atomic accumulators ----------
__global__ void bn_finalize(const float* __restrict__ stat_acc,
                            float2* __restrict__ stats, int C) {
  int c = blockIdx.x * 256 + threadIdx.x;
  if (c < C) {
    float m   = stat_acc[c] * (1.0f / NTOT);
    float var = stat_acc[C + c] * (1.0f / NTOT) - m * m;
    stats[c] = make_float2(m, rsqrtf(var + 1e-5f));
  }
}

// ---------- global-feature branch of layer 6 ----------
__global__ __launch_bounds__(256) void pool_const6(
    const unsigned* __restrict__ max_acc, const float2* __restrict__ stats5,
    const float* __restrict__ w6, float* __restrict__ cst)
{
  __shared__ __align__(16) float4 P[1024];
  int b = blockIdx.x;
  for (int c = threadIdx.x; c < 1024; c += 256) {
    float mx = decf(max_acc[(b << 10) + c]);
    float2 s = stats5[c];
    float tt = fast_tanh((mx - s.x) * s.y);
    float p0, p1, p2, p3; jacobi4(tt, p0, p1, p2, p3);
    P[c] = make_float4(p0, p1, p2, p3);
  }
  __syncthreads();
  for (int o = threadIdx.x; o < 512; o += 256) {
    float a = 0.f;
    for (int c = 0; c < 1024; ++c) {
      float4 wv = *(const float4*)(w6 + (((size_t)(64 + c) * 512 + o) << 2));
      float4 p  = P[c];
      a += p.x * wv.x + p.y * wv.y + p.z * wv.z + p.w * wv.w;
    }
    cst[(b << 9) + o] = a;
  }
}

// ---------- final layer: C_in=128 -> C_out=3 ----------
__global__ __launch_bounds__(256) void kan_final(
    const float* __restrict__ in, const float2* __restrict__ stats,
    const float* __restrict__ w, float* __restrict__ out)
{
  int g = blockIdx.x * 256 + threadIdx.x;
  int b = g >> 10, n = g & 1023;
  float a0 = 0.f, a1 = 0.f, a2 = 0.f;
  for (int i = 0; i < 128; ++i) {
    float v = in[((size_t)(b * 128 + i) << 10) + n];
    float2 s = stats[i];
    float p0, p1, p2, p3; jacobi4(fast_tanh((v - s.x) * s.y), p0, p1, p2, p3);
    const float4 w0 = *(const float4*)(w + ((i * 3 + 0) << 2));
    const float4 w1 = *(const float4*)(w + ((i * 3 + 1) << 2));
    const float4 w2 = *(const float4*)(w + ((i * 3 + 2) << 2));
    a0 += p0 * w0.x + p1 * w0.y + p2 * w0.z + p3 * w0.w;
    a1 += p0 * w1.x + p1 * w1.y + p2 * w1.z + p3 * w1.w;
    a2 += p0 * w2.x + p1 * w2.y + p2 * w2.z + p3 * w2.w;
  }
  out[((b * 3 + 0) << 10) + n] = a0;
  out[((b * 3 + 1) << 10) + n] = a1;
  out[((b * 3 + 2) << 10) + n] = a2;
}

// ---------- launch ----------
extern "C" void kernel_launch(void* const* d_in, const int* in_sizes, int n_in,
                              void* d_out, int out_size, void* d_ws, size_t ws_size,
                              hipStream_t stream) {
  const float* x   = (const float*)d_in[0];
  const float* w1  = (const float*)d_in[1];
  const float* w2  = (const float*)d_in[2];
  const float* w3  = (const float*)d_in[3];
  const float* w4  = (const float*)d_in[4];
  const float* w5  = (const float*)d_in[5];
  const float* w6  = (const float*)d_in[6];
  const float* w7  = (const float*)d_in[7];
  const float* w8  = (const float*)d_in[8];
  const float* w9  = (const float*)d_in[9];
  const float* w10 = (const float*)d_in[10];

  float* ws = (float*)d_ws;
  float*    stat_acc = ws + 0;                      // 2048
  unsigned* maxenc   = (unsigned*)(ws + 2048);      // 32768 words
  float2*   spart    = (float2*)(ws + 34816);       // 131072 float2
  float2*   stats1   = (float2*)(ws + 296960);
  float2*   stats2   = stats1 + 64;
  float2*   stats3   = stats2 + 64;
  float2*   stats4   = stats3 + 64;
  float2*   stats5   = stats4 + 128;
  float2*   stats6   = stats5 + 1024;
  float2*   stats7   = stats6 + 512;
  float2*   stats8   = stats7 + 256;
  float2*   stats9   = stats8 + 128;
  float*    cst6     = ws + 301696;                 // 16384 (32 x 512)
  float*    A0       = ws + 327680;                 // 2M floats (y1, y3)
  float*    A1       = A0 + 2097152;                // 4M (y4, y9)
  float*    A2       = A1 + 4194304;                // 2M (y2, kept for layer 6)
  float*    A3       = A2 + 2097152;                // 16M (y6, then y8)
  float*    A4       = A3 + 16777216;               // 8M (y7)
  // total ~135.5 MB (same proven footprint as R1/R2)

  dim3 blk(256);
  zero_ws<<<136, blk, 0, stream>>>((unsigned*)ws, 34816);

  // L1: 2 -> 64 fp32 (proven <256,64> config, grid 128)
  kan_gemm<256, 64><<<dim3(128, 1), blk, 0, stream>>>(x, nullptr, w1, A0, spart, 2, 64);
  bn_finalize2<<<64, blk, 0, stream>>>(spart, stats1, 64, 128);
  // L2: 64 -> 64 fp32 (local feature, kept)
  kan_gemm<256, 64><<<dim3(128, 1), blk, 0, stream>>>(A0, stats1, w2, A2, spart, 64, 64);
  bn_finalize2<<<64, blk, 0, stream>>>(spart, stats2, 64, 128);
  // L3: 64 -> 64 fp32
  kan_gemm<256, 64><<<dim3(128, 1), blk, 0, stream>>>(A2, stats2, w3, A0, spart, 64, 64);
  bn_finalize2<<<64, blk, 0, stream>>>(spart, stats3, 64, 128);
  // L4: 64 -> 128 MFMA
  kan_mfma<<<dim3(256, 1), blk, 0, stream>>>(A0, stats3, w4, nullptr, A1, spart, nullptr, nullptr, 64, 128);
  bn_finalize2<<<128, blk, 0, stream>>>(spart, stats4, 128, 256);
  // L5: 128 -> 1024 MFMA, fused stats + maxpool, no materialization
  kan_mfma<<<dim3(256, 8), blk, 0, stream>>>(A1, stats4, w5, nullptr, nullptr, nullptr, stat_acc, maxenc, 128, 1024);
  bn_finalize<<<4, blk, 0, stream>>>(stat_acc, stats5, 1024);
  // gf branch of layer 6 (constant over n)
  pool_const6<<<32, blk, 0, stream>>>(maxenc, stats5, w6, cst6);
  // L6: 64 (local) -> 512 MFMA + gf bias
  kan_mfma<<<dim3(256, 4), blk, 0, stream>>>(A2, stats2, w6, cst6, A3, spart, nullptr, nullptr, 64, 512);
  bn_finalize2<<<512, blk, 0, stream>>>(spart, stats6, 512, 256);
  // L7: 512 -> 256 MFMA
  kan_mfma<<<dim3(256, 2), blk, 0, stream>>>(A3, stats6, w7, nullptr, A4, spart, nullptr, nullptr, 512, 256);
  bn_finalize2<<<256, blk, 0, stream>>>(spart, stats7, 256, 256);
  // L8: 256 -> 128 MFMA (y8 reuses y6 region)
  kan_mfma<<<dim3(256, 1), blk, 0, stream>>>(A4, stats7, w8, nullptr, A3, spart, nullptr, nullptr, 256, 128);
  bn_finalize2<<<128, blk, 0, stream>>>(spart, stats8, 128, 256);
  // L9: 128 -> 128 MFMA
  kan_mfma<<<dim3(256, 1), blk, 0, stream>>>(A3, stats8, w9, nullptr, A1, spart, nullptr, nullptr, 128, 128);
  bn_finalize2<<<128, blk, 0, stream>>>(spart, stats9, 128, 256);
  // L10: 128 -> 3 fp32
  kan_final<<<128, blk, 0, stream>>>(A1, stats9, w10, (float*)d_out);
}

// Round 5
// 566.169 us; speedup vs baseline: 3.4327x; 1.4944x over previous
//
#include <hip/hip_runtime.h>

#define BATCH 32
#define NPTS  1024
#define NTOT  (BATCH * NPTS)   // 32768 points

typedef _Float16 half8 __attribute__((ext_vector_type(8)));
typedef float    f32x4 __attribute__((ext_vector_type(4)));

// ---------- helpers ----------

__device__ __forceinline__ float fast_tanh(float x) {
  float ax = fabsf(x);
  float e  = __expf(-2.0f * ax);
  float t  = (1.0f - e) / (1.0f + e);
  return x < 0.0f ? -t : t;
}

// Jacobi polys for a=b=1, degree 3: p1=2t, p2=3.75t^2-0.75, p3=7t^3-3t
__device__ __forceinline__ void jacobi4(float t, float& p0, float& p1, float& p2, float& p3) {
  float t2 = t * t;
  p0 = 1.0f;
  p1 = 2.0f * t;
  p2 = 3.75f * t2 - 0.75f;
  p3 = t * (7.0f * t2 - 3.0f);
}

// monotone float<->uint encoding for atomicMax over signed floats
__device__ __forceinline__ unsigned encf(float f) {
  unsigned b = __float_as_uint(f);
  return b ^ ((unsigned)((int)b >> 31) | 0x80000000u);
}
__device__ __forceinline__ float decf(unsigned u) {
  unsigned b = (u & 0x80000000u) ? (u ^ 0x80000000u) : ~u;
  return __uint_as_float(b);
}

// ---------- zero workspace accumulators ----------
__global__ void zero_ws(unsigned* __restrict__ p, int n) {
  int i = blockIdx.x * 256 + threadIdx.x;
  if (i < n) p[i] = 0u;
}

// ---------- weight preconversion: fp32 (C_in, C_out, 4) -> fp16 x64, fragment layout ----------
// Wh[(ot*(C_in/2) + s)*128 + oL] = half8{ 64*w[2s][ot*128+oL][0..3], 64*w[2s+1][...][0..3] }
__global__ void conv_w16(const float* __restrict__ w, half8* __restrict__ wh,
                         int C_in, int C_out) {
  const int nslot = C_in >> 1;
  int tid = blockIdx.x * 256 + threadIdx.x;
  int oL = tid & 127;
  int r  = tid >> 7;
  int s  = r % nslot;
  int ot = r / nslot;
  int i  = s << 1;
  int o  = (ot << 7) + oL;
  const float4 wa = *(const float4*)(w + (((size_t)i * C_out + o) << 2));
  const float4 wb = *(const float4*)(w + (((size_t)(i + 1) * C_out + o) << 2));
  half8 h;
  h[0] = (_Float16)(wa.x * 64.0f); h[1] = (_Float16)(wa.y * 64.0f);
  h[2] = (_Float16)(wa.z * 64.0f); h[3] = (_Float16)(wa.w * 64.0f);
  h[4] = (_Float16)(wb.x * 64.0f); h[5] = (_Float16)(wb.y * 64.0f);
  h[6] = (_Float16)(wb.z * 64.0f); h[7] = (_Float16)(wb.w * 64.0f);
  wh[tid] = h;
}

// ---------- MFMA KAN layer v2: barrier-free, LDS-free K-loop ----------
// Block: 128 pts x 128 outs, 4 waves (2x2 of 64x64 wave tiles, 4x4 frags of 16x16x32).
// A-fragments computed in registers per wave (y load + tanh + Jacobi, fp16 pack).
// B-fragments loaded directly from preconverted Wh (global, L2-resident).
// Lane's slot sequence: s = quad, quad+4, ... (slot s = channels 2s,2s+1, k=quad*8+j).
// Verified layouts: A m=lane&15, k=quad*8+j; C/D row(M)=quad*4+reg, col(N)=lane&15.
// Epilogue (unchanged from R4-proven):
//   out != nullptr : write y + per-(o, xblock) partials to spart
//   out == nullptr : L5 mode -> atomicAdd channel sums + per-(b,o) atomicMax
__global__ __launch_bounds__(256, 2) void kan_mfma2(
    const float*  __restrict__ in,      // (B, C_in, N) fp32
    const float2* __restrict__ stats,   // per-in-channel (mean, rstd)
    const half8*  __restrict__ wh,      // preconverted weights (x64)
    const float*  __restrict__ bias,    // (B, C_out) or nullptr
    float*        __restrict__ out,     // (B, C_out, N) or nullptr
    float2*       __restrict__ spart,   // (C_out, 256) partials
    float*        __restrict__ stat_acc,// (2*C_out) atomic sums (L5 mode)
    unsigned*     __restrict__ max_acc, // (B*C_out) encoded max (L5 mode)
    int C_in, int C_out)
{
  __shared__ float sredS[128][2], sredS2[128][2], sredM[128][2];

  const int t    = threadIdx.x;
  const int lane = t & 63;
  const int col  = lane & 15;
  const int quad = lane >> 4;
  const int wv   = t >> 6;
  const int wm   = wv & 1;
  const int wn   = wv >> 1;
  const int b    = blockIdx.x >> 3;
  const int n0   = (blockIdx.x & 7) << 7;
  const int o0   = blockIdx.y << 7;
  const int nslot = C_in >> 1;

  f32x4 acc[4][4];
#pragma unroll
  for (int i = 0; i < 4; ++i)
#pragma unroll
    for (int j = 0; j < 4; ++j)
#pragma unroll
      for (int k = 0; k < 4; ++k) acc[i][j][k] = 0.0f;

  // wave-invariant bases
  const float* yb = in + ((size_t)b * C_in << 10) + n0 + (wm << 6) + col;
  const half8* Bb = wh + (((size_t)blockIdx.y * nslot) << 7) + (wn << 6) + col;

  for (int s = quad; s < nslot; s += 4) {
    const int i2 = s << 1;
    const float2 st0 = stats[i2], st1 = stats[i2 + 1];
    const float* y0 = yb + ((size_t)i2 << 10);
    half8 af[4], bf[4];
#pragma unroll
    for (int f = 0; f < 4; ++f) {
      float v0 = y0[(f << 4)];
      float v1 = y0[(f << 4) + 1024];
      bf[f] = Bb[((size_t)s << 7) + (f << 4)];
      float t0 = fast_tanh((v0 - st0.x) * st0.y);
      float t1 = fast_tanh((v1 - st1.x) * st1.y);
      float p0, p1, p2, p3, q0, q1, q2, q3;
      jacobi4(t0, p0, p1, p2, p3);
      jacobi4(t1, q0, q1, q2, q3);
      half8 h;
      h[0] = (_Float16)p0; h[1] = (_Float16)p1; h[2] = (_Float16)p2; h[3] = (_Float16)p3;
      h[4] = (_Float16)q0; h[5] = (_Float16)q1; h[6] = (_Float16)q2; h[7] = (_Float16)q3;
      af[f] = h;
    }
#pragma unroll
    for (int fm = 0; fm < 4; ++fm)
#pragma unroll
      for (int fn = 0; fn < 4; ++fn)
        acc[fm][fn] = __builtin_amdgcn_mfma_f32_16x16x32_f16(af[fm], bf[fn], acc[fm][fn], 0, 0, 0);
  }

  // ---- epilogue: unscale, bias, write, fused BN stats ----
  const float inv64 = 0.015625f;
#pragma unroll
  for (int fn = 0; fn < 4; ++fn) {
    const int cl = (wn << 6) + (fn << 4) + col;
    const int o  = o0 + cl;
    const float bb = bias ? bias[b * C_out + o] : 0.0f;
    float s = 0.f, s2 = 0.f, mx = -3.4e38f;
#pragma unroll
    for (int fm = 0; fm < 4; ++fm) {
      float v0 = acc[fm][fn][0] * inv64 + bb;
      float v1 = acc[fm][fn][1] * inv64 + bb;
      float v2 = acc[fm][fn][2] * inv64 + bb;
      float v3 = acc[fm][fn][3] * inv64 + bb;
      if (out) {
        *(float4*)(out + (((size_t)(b * C_out + o)) << 10) + n0 + (wm << 6) + (fm << 4) + (quad << 2)) =
            make_float4(v0, v1, v2, v3);
      }
      s  += v0 + v1 + v2 + v3;
      s2 += v0 * v0 + v1 * v1 + v2 * v2 + v3 * v3;
      mx  = fmaxf(fmaxf(v0, v1), fmaxf(fmaxf(v2, v3), mx));
    }
    s  += __shfl_down(s, 32);  s  += __shfl_down(s, 16);
    s2 += __shfl_down(s2, 32); s2 += __shfl_down(s2, 16);
    mx  = fmaxf(mx, __shfl_down(mx, 32)); mx = fmaxf(mx, __shfl_down(mx, 16));
    if (lane < 16) {
      sredS [cl][wm] = s;
      sredS2[cl][wm] = s2;
      sredM [cl][wm] = mx;
    }
  }
  __syncthreads();
  if (t < 128) {
    const int o = o0 + t;
    float s  = sredS [t][0] + sredS [t][1];
    float s2 = sredS2[t][0] + sredS2[t][1];
    if (out) {
      spart[(o << 8) + blockIdx.x] = make_float2(s, s2);
    } else {
      float mx = fmaxf(sredM[t][0], sredM[t][1]);
      atomicAdd(&stat_acc[o], s);
      atomicAdd(&stat_acc[C_out + o], s2);
      atomicMax(&max_acc[b * C_out + o], encf(mx));
    }
  }
}

// ---------- fp32 KAN layer (small layers L1-L3) ----------
// 256 threads, 8x8 outputs per thread => REQUIRES BM*BN == 16384.
template<int BM, int BN>
__global__ __launch_bounds__(256) void kan_gemm(
    const float*  __restrict__ in, const float2* __restrict__ stats,
    const float*  __restrict__ w, float* __restrict__ out,
    float2* __restrict__ spart, int C_in, int C_out)
{
  static_assert(BM * BN == 256 * 64, "8x8-per-thread tile requires BM*BN == 16384");
  constexpr int TM = BM / 8;
  constexpr int AE = 8 * BM / 256;
  constexpr int BE = 8 * BN / 256;
  __shared__ __align__(16) float As[32][BM];
  __shared__ __align__(16) float Bs[32][BN];

  const int t  = threadIdx.x;
  const int tpb = NPTS / BM;
  const int b  = blockIdx.x / tpb;
  const int n0 = (blockIdx.x % tpb) * BM;
  const int o0 = blockIdx.y * BN;
  const int tm = t % TM;
  const int to = t / TM;

  float acc[2][4][2][4];
#pragma unroll
  for (int a = 0; a < 2; ++a)
#pragma unroll
    for (int c = 0; c < 4; ++c)
#pragma unroll
      for (int d = 0; d < 2; ++d)
#pragma unroll
        for (int e = 0; e < 4; ++e) acc[a][c][d][e] = 0.0f;

  const int nch = (C_in + 7) >> 3;
  for (int ch = 0; ch < nch; ++ch) {
    const int i0 = ch << 3;
    __syncthreads();
#pragma unroll
    for (int r = 0; r < AE; ++r) {
      int e  = t + (r << 8);
      int il = e / BM, n = e % BM;
      int i  = i0 + il;
      float p0 = 0.f, p1 = 0.f, p2 = 0.f, p3 = 0.f;
      if (i < C_in) {
        float v = in[((size_t)(b * C_in + i) << 10) + n0 + n];
        if (stats) { float2 s = stats[i]; v = (v - s.x) * s.y; }
        jacobi4(fast_tanh(v), p0, p1, p2, p3);
      }
      As[(il << 2) + 0][n] = p0;
      As[(il << 2) + 1][n] = p1;
      As[(il << 2) + 2][n] = p2;
      As[(il << 2) + 3][n] = p3;
    }
#pragma unroll
    for (int r = 0; r < BE; ++r) {
      int e  = t + (r << 8);
      int il = e / BN, o = e % BN;
      int i  = i0 + il;
      float4 wv = make_float4(0.f, 0.f, 0.f, 0.f);
      if (i < C_in) wv = *(const float4*)(w + (((size_t)i * C_out + o0 + o) << 2));
      Bs[(il << 2) + 0][o] = wv.x;
      Bs[(il << 2) + 1][o] = wv.y;
      Bs[(il << 2) + 2][o] = wv.z;
      Bs[(il << 2) + 3][o] = wv.w;
    }
    __syncthreads();
#pragma unroll 8
    for (int k = 0; k < 32; ++k) {
      const float4 a0 = *(const float4*)&As[k][tm << 2];
      const float4 a1 = *(const float4*)&As[k][(BM / 2) + (tm << 2)];
      const float4 b0 = *(const float4*)&Bs[k][to << 2];
      const float4 b1 = *(const float4*)&Bs[k][(BN / 2) + (to << 2)];
      const float am[2][4] = {{a0.x, a0.y, a0.z, a0.w}, {a1.x, a1.y, a1.z, a1.w}};
      const float bo[2][4] = {{b0.x, b0.y, b0.z, b0.w}, {b1.x, b1.y, b1.z, b1.w}};
#pragma unroll
      for (int oh = 0; oh < 2; ++oh)
#pragma unroll
        for (int oj = 0; oj < 4; ++oj) {
          const float bv = bo[oh][oj];
#pragma unroll
          for (int mh = 0; mh < 2; ++mh)
#pragma unroll
            for (int mj = 0; mj < 4; ++mj)
              acc[oh][oj][mh][mj] = fmaf(bv, am[mh][mj], acc[oh][oj][mh][mj]);
        }
    }
  }

#pragma unroll
  for (int oh = 0; oh < 2; ++oh)
#pragma unroll
    for (int oj = 0; oj < 4; ++oj) {
      const int o = o0 + oh * (BN / 2) + (to << 2) + oj;
      float s = 0.f, s2 = 0.f;
#pragma unroll
      for (int mh = 0; mh < 2; ++mh) {
        float4 v = make_float4(acc[oh][oj][mh][0], acc[oh][oj][mh][1],
                               acc[oh][oj][mh][2], acc[oh][oj][mh][3]);
        *(float4*)(out + (((size_t)(b * C_out + o)) << 10) + n0 + mh * (BM / 2) + (tm << 2)) = v;
        s  += v.x + v.y + v.z + v.w;
        s2 += v.x * v.x + v.y * v.y + v.z * v.z + v.w * v.w;
      }
#pragma unroll
      for (int off = TM / 2; off > 0; off >>= 1) {
        s  += __shfl_down(s, off, TM);
        s2 += __shfl_down(s2, off, TM);
      }
      if (tm == 0) spart[(o << 8) + blockIdx.x] = make_float2(s, s2);
    }
}

// ---------- reduce per-block partials -> BN stats ----------
__global__ __launch_bounds__(256) void bn_finalize2(
    const float2* __restrict__ spart, float2* __restrict__ stats, int C, int nxb)
{
  int c = blockIdx.x, t = threadIdx.x;
  float s = 0.f, s2 = 0.f;
  if (t < nxb) { float2 p = spart[(c << 8) + t]; s = p.x; s2 = p.y; }
#pragma unroll
  for (int off = 32; off > 0; off >>= 1) {
    s  += __shfl_down(s, off);
    s2 += __shfl_down(s2, off);
  }
  __shared__ float rs[4], rs2[4];
  int wid = t >> 6;
  if ((t & 63) == 0) { rs[wid] = s; rs2[wid] = s2; }
  __syncthreads();
  if (t == 0) {
    s  = rs[0] + rs[1] + rs[2] + rs[3];
    s2 = rs2[0] + rs2[1] + rs2[2] + rs2[3];
    float m   = s * (1.0f / NTOT);
    float var = s2 * (1.0f / NTOT) - m * m;
    stats[c] = make_float2(m, rsqrtf(var + 1e-5f));
  }
}

// ---------- finalize layer-5 stats from atomic accumulators ----------
__global__ void bn_finalize(const float* __restrict__ stat_acc,
                            float2* __restrict__ stats, int C) {
  int c = blockIdx.x * 256 + threadIdx.x;
  if (c < C) {
    float m   = stat_acc[c] * (1.0f / NTOT);
    float var = stat_acc[C + c] * (1.0f / NTOT) - m * m;
    stats[c] = make_float2(m, rsqrtf(var + 1e-5f));
  }
}

// ---------- global-feature branch of layer 6, parallel ----------
// grid (8 o-tiles of 64, 16 c-chunks of 64); atomicAdd partials into zeroed cst.
__global__ __launch_bounds__(256) void pool_const6p(
    const unsigned* __restrict__ max_acc, const float2* __restrict__ stats5,
    const float* __restrict__ w6, float* __restrict__ cst)
{
  __shared__ __align__(16) float4 P[32][64];
  const int t  = threadIdx.x;
  const int ot = blockIdx.x;         // 64 outputs
  const int c0 = blockIdx.y << 6;    // 64 channels
#pragma unroll
  for (int it = 0; it < 8; ++it) {
    int idx = t + (it << 8);
    int b = idx >> 6, cl = idx & 63;
    int c = c0 + cl;
    float mx = decf(max_acc[(b << 10) + c]);
    float2 s = stats5[c];
    float tt = fast_tanh((mx - s.x) * s.y);
    float p0, p1, p2, p3; jacobi4(tt, p0, p1, p2, p3);
    P[b][cl] = make_float4(p0, p1, p2, p3);
  }
  __syncthreads();
  const int oL = t & 63;
  const int bg = t >> 6;             // 4 groups x 8 batches
  const int o  = (ot << 6) + oL;
  float acc[8];
#pragma unroll
  for (int i = 0; i < 8; ++i) acc[i] = 0.f;
  for (int cl = 0; cl < 64; ++cl) {
    const float4 wv = *(const float4*)(w6 + (((size_t)(64 + c0 + cl) * 512 + o) << 2));
#pragma unroll
    for (int bb = 0; bb < 8; ++bb) {
      float4 p = P[(bg << 3) + bb][cl];
      acc[bb] += p.x * wv.x + p.y * wv.y + p.z * wv.z + p.w * wv.w;
    }
  }
#pragma unroll
  for (int bb = 0; bb < 8; ++bb)
    atomicAdd(&cst[(((bg << 3) + bb) << 9) + o], acc[bb]);
}

// ---------- final layer: C_in=128 -> C_out=3 ----------
__global__ __launch_bounds__(256) void kan_final(
    const float* __restrict__ in, const float2* __restrict__ stats,
    const float* __restrict__ w, float* __restrict__ out)
{
  int g = blockIdx.x * 256 + threadIdx.x;
  int b = g >> 10, n = g & 1023;
  float a0 = 0.f, a1 = 0.f, a2 = 0.f;
  for (int i = 0; i < 128; ++i) {
    float v = in[((size_t)(b * 128 + i) << 10) + n];
    float2 s = stats[i];
    float p0, p1, p2, p3; jacobi4(fast_tanh((v - s.x) * s.y), p0, p1, p2, p3);
    const float4 w0 = *(const float4*)(w + ((i * 3 + 0) << 2));
    const float4 w1 = *(const float4*)(w + ((i * 3 + 1) << 2));
    const float4 w2 = *(const float4*)(w + ((i * 3 + 2) << 2));
    a0 += p0 * w0.x + p1 * w0.y + p2 * w0.z + p3 * w0.w;
    a1 += p0 * w1.x + p1 * w1.y + p2 * w1.z + p3 * w1.w;
    a2 += p0 * w2.x + p1 * w2.y + p2 * w2.z + p3 * w2.w;
  }
  out[((b * 3 + 0) << 10) + n] = a0;
  out[((b * 3 + 1) << 10) + n] = a1;
  out[((b * 3 + 2) << 10) + n] = a2;
}

// ---------- launch ----------
extern "C" void kernel_launch(void* const* d_in, const int* in_sizes, int n_in,
                              void* d_out, int out_size, void* d_ws, size_t ws_size,
                              hipStream_t stream) {
  const float* x   = (const float*)d_in[0];
  const float* w1  = (const float*)d_in[1];
  const float* w2  = (const float*)d_in[2];
  const float* w3  = (const float*)d_in[3];
  const float* w4  = (const float*)d_in[4];
  const float* w5  = (const float*)d_in[5];
  const float* w6  = (const float*)d_in[6];
  const float* w7  = (const float*)d_in[7];
  const float* w8  = (const float*)d_in[8];
  const float* w9  = (const float*)d_in[9];
  const float* w10 = (const float*)d_in[10];

  float* ws = (float*)d_ws;
  // workspace layout (floats)
  float*    stat_acc = ws + 0;                      // 2048
  unsigned* maxenc   = (unsigned*)(ws + 2048);      // 32768 words
  float*    cst6     = ws + 34816;                  // 16384 (32 x 512) — zeroed
  float2*   spart    = (float2*)(ws + 51200);       // 131072 float2
  float2*   stats1   = (float2*)(ws + 313344);
  float2*   stats2   = stats1 + 64;
  float2*   stats3   = stats2 + 64;
  float2*   stats4   = stats3 + 64;
  float2*   stats5   = stats4 + 128;
  float2*   stats6   = stats5 + 1024;
  float2*   stats7   = stats6 + 512;
  float2*   stats8   = stats7 + 256;
  float2*   stats9   = stats8 + 128;
  // fp16 weight pool (half8 units)
  half8*    whbase = (half8*)(ws + 318464);
  half8*    h4 = whbase + 0;        // 64x128x4   -> 4096 half8
  half8*    h5 = whbase + 4096;     // 128x1024x4 -> 65536
  half8*    h6 = whbase + 69632;    // 64x512x4   -> 16384
  half8*    h7 = whbase + 86016;    // 512x256x4  -> 65536
  half8*    h8 = whbase + 151552;   // 256x128x4  -> 16384
  half8*    h9 = whbase + 167936;   // 128x128x4  -> 8192 (ends 176128 = 704512 floats)
  float*    A0       = ws + 1048576;                // 2M floats (y1, y3)
  float*    A1       = A0 + 2097152;                // 4M (y4, y9)
  float*    A2       = A1 + 4194304;                // 2M (y2, kept for layer 6)
  float*    A3       = A2 + 2097152;                // 16M (y6, then y8)
  float*    A4       = A3 + 16777216;               // 8M (y7)
  // total ~138.4 MB

  dim3 blk(256);
  zero_ws<<<200, blk, 0, stream>>>((unsigned*)ws, 51200);
  // preconvert weights (independent of dataflow)
  conv_w16<<<16,  blk, 0, stream>>>(w4, h4, 64, 128);
  conv_w16<<<256, blk, 0, stream>>>(w5, h5, 128, 1024);
  conv_w16<<<64,  blk, 0, stream>>>(w6, h6, 64, 512);   // local rows 0..63 only
  conv_w16<<<256, blk, 0, stream>>>(w7, h7, 512, 256);
  conv_w16<<<64,  blk, 0, stream>>>(w8, h8, 256, 128);
  conv_w16<<<32,  blk, 0, stream>>>(w9, h9, 128, 128);

  // L1: 2 -> 64 fp32
  kan_gemm<256, 64><<<dim3(128, 1), blk, 0, stream>>>(x, nullptr, w1, A0, spart, 2, 64);
  bn_finalize2<<<64, blk, 0, stream>>>(spart, stats1, 64, 128);
  // L2: 64 -> 64 fp32 (local feature, kept)
  kan_gemm<256, 64><<<dim3(128, 1), blk, 0, stream>>>(A0, stats1, w2, A2, spart, 64, 64);
  bn_finalize2<<<64, blk, 0, stream>>>(spart, stats2, 64, 128);
  // L3: 64 -> 64 fp32
  kan_gemm<256, 64><<<dim3(128, 1), blk, 0, stream>>>(A2, stats2, w3, A0, spart, 64, 64);
  bn_finalize2<<<64, blk, 0, stream>>>(spart, stats3, 64, 128);
  // L4: 64 -> 128 MFMA
  kan_mfma2<<<dim3(256, 1), blk, 0, stream>>>(A0, stats3, h4, nullptr, A1, spart, nullptr, nullptr, 64, 128);
  bn_finalize2<<<128, blk, 0, stream>>>(spart, stats4, 128, 256);
  // L5: 128 -> 1024 MFMA, fused stats + maxpool, no materialization
  kan_mfma2<<<dim3(256, 8), blk, 0, stream>>>(A1, stats4, h5, nullptr, nullptr, nullptr, stat_acc, maxenc, 128, 1024);
  bn_finalize<<<4, blk, 0, stream>>>(stat_acc, stats5, 1024);
  // gf branch of layer 6 (constant over n)
  pool_const6p<<<dim3(8, 16), blk, 0, stream>>>(maxenc, stats5, w6, cst6);
  // L6: 64 (local) -> 512 MFMA + gf bias
  kan_mfma2<<<dim3(256, 4), blk, 0, stream>>>(A2, stats2, h6, cst6, A3, spart, nullptr, nullptr, 64, 512);
  bn_finalize2<<<512, blk, 0, stream>>>(spart, stats6, 512, 256);
  // L7: 512 -> 256 MFMA
  kan_mfma2<<<dim3(256, 2), blk, 0, stream>>>(A3, stats6, h7, nullptr, A4, spart, nullptr, nullptr, 512, 256);
  bn_finalize2<<<256, blk, 0, stream>>>(spart, stats7, 256, 256);
  // L8: 256 -> 128 MFMA (y8 reuses y6 region)
  kan_mfma2<<<dim3(256, 1), blk, 0, stream>>>(A4, stats7, h8, nullptr, A3, spart, nullptr, nullptr, 256, 128);
  bn_finalize2<<<128, blk, 0, stream>>>(spart, stats8, 128, 256);
  // L9: 128 -> 128 MFMA
  kan_mfma2<<<dim3(256, 1), blk, 0, stream>>>(A3, stats8, h9, nullptr, A1, spart, nullptr, nullptr, 128, 128);
  bn_finalize2<<<128, blk, 0, stream>>>(spart, stats9, 128, 256);
  // L10: 128 -> 3 fp32
  kan_final<<<128, blk, 0, stream>>>(A1, stats9, w10, (float*)d_out);
}

// Round 7
// 421.346 us; speedup vs baseline: 4.6125x; 1.3437x over previous
//
#include <hip/hip_runtime.h>

#define BATCH 32
#define NPTS  1024
#define NTOT  (BATCH * NPTS)   // 32768 points

typedef _Float16 half8  __attribute__((ext_vector_type(8)));
typedef _Float16 half4v __attribute__((ext_vector_type(4)));
typedef float    f32x4  __attribute__((ext_vector_type(4)));

// ---------- helpers ----------

__device__ __forceinline__ float fast_tanh(float x) {
  float ax = fabsf(x);
  float e  = __expf(-2.0f * ax);
  float t  = (1.0f - e) / (1.0f + e);
  return x < 0.0f ? -t : t;
}

// Jacobi polys for a=b=1, degree 3: p1=2t, p2=3.75t^2-0.75, p3=7t^3-3t
__device__ __forceinline__ void jacobi4(float t, float& p0, float& p1, float& p2, float& p3) {
  float t2 = t * t;
  p0 = 1.0f;
  p1 = 2.0f * t;
  p2 = 3.75f * t2 - 0.75f;
  p3 = t * (7.0f * t2 - 3.0f);
}

// monotone float<->uint encoding for atomicMax over signed floats
__device__ __forceinline__ unsigned encf(float f) {
  unsigned b = __float_as_uint(f);
  return b ^ ((unsigned)((int)b >> 31) | 0x80000000u);
}
__device__ __forceinline__ float decf(unsigned u) {
  unsigned b = (u & 0x80000000u) ? (u ^ 0x80000000u) : ~u;
  return __uint_as_float(b);
}

// ---------- zero workspace accumulators ----------
__global__ void zero_ws(unsigned* __restrict__ p, int n) {
  int i = blockIdx.x * 256 + threadIdx.x;
  if (i < n) p[i] = 0u;
}

// ---------- weight preconversion: fp32 (C_in, C_out, 4) -> fp16 x64, fragment layout ----------
// wh[(ot*nslot + s)*BN + oL] = half8{ 64*w[2s][ot*BN+oL][0..3], 64*w[2s+1][...][0..3] }
__global__ void conv_w16(const float* __restrict__ w, half8* __restrict__ wh,
                         int C_in, int C_out, int BN) {
  const int nslot = C_in >> 1;
  int tid = blockIdx.x * 256 + threadIdx.x;
  int oL = tid % BN;
  int r  = tid / BN;
  int s  = r % nslot;
  int ot = r / nslot;
  int i  = s << 1;
  int o  = ot * BN + oL;
  const float4 wa = *(const float4*)(w + (((size_t)i * C_out + o) << 2));
  const float4 wb = *(const float4*)(w + (((size_t)(i + 1) * C_out + o) << 2));
  half8 h;
  h[0] = (_Float16)(wa.x * 64.0f); h[1] = (_Float16)(wa.y * 64.0f);
  h[2] = (_Float16)(wa.z * 64.0f); h[3] = (_Float16)(wa.w * 64.0f);
  h[4] = (_Float16)(wb.x * 64.0f); h[5] = (_Float16)(wb.y * 64.0f);
  h[6] = (_Float16)(wb.z * 64.0f); h[7] = (_Float16)(wb.w * 64.0f);
  wh[tid] = h;
}

// ---------- activation pass: y <- tanh(norm(y)) IN PLACE, fp32 ----------
// layout (B, C, N); grid = 32*C blocks x 256 threads x 4 floats.
__global__ __launch_bounds__(256) void act_tanh(
    float* y, const float2* __restrict__ st, int C)
{
  size_t i = (((size_t)blockIdx.x << 8) + threadIdx.x) << 2;
  int c = (int)((i >> 10) % (unsigned)C);
  float2 s = st[c];
  float4 v = *(float4*)(y + i);
  v.x = fast_tanh((v.x - s.x) * s.y);
  v.y = fast_tanh((v.y - s.x) * s.y);
  v.z = fast_tanh((v.z - s.x) * s.y);
  v.w = fast_tanh((v.w - s.x) * s.y);
  *(float4*)(y + i) = v;
}

// ---------- MFMA KAN layer v3: reads precomputed fp32 tanh, Jacobi in fp32, packs fp16 ----------
// Block: 128 pts x BN outs (BN = NBW*64), 2*NBW waves (2 m-tiles x NBW n-tiles of 64,
// 4x4 frags of mfma_f32_16x16x32_f16). A-frag: two fp32 t per slot, polys fp32 -> fp16.
// Verified layouts: A m=lane&15, k=quad*8+j; C/D row(M)=quad*4+reg, col(N)=lane&15.
// Weights pre-scaled x64 (undone in epilogue). Epilogue:
//   out != nullptr : write fp32 y + per-(o, xblock) partials to spart
//   out == nullptr : L5 mode -> atomicAdd channel sums + per-(b,o) atomicMax
template<int NBW>
__global__ __launch_bounds__(NBW * 128, 2) void kan_mfma3(
    const float* __restrict__ T,       // (B, C_in, N) fp32 tanh values
    const half8* __restrict__ wh,      // preconverted weights (x64)
    const float* __restrict__ bias,    // (B, C_out) or nullptr
    float*       __restrict__ out,     // (B, C_out, N) fp32 or nullptr
    float2*      __restrict__ spart,   // (C_out, 256) partials
    float*       __restrict__ stat_acc,
    unsigned*    __restrict__ max_acc,
    int C_in, int C_out)
{
  constexpr int BN = NBW * 64;
  const int nslot = C_in >> 1;
  __shared__ float sredS[BN][2], sredS2[BN][2], sredM[BN][2];

  const int t    = threadIdx.x;
  const int lane = t & 63;
  const int col  = lane & 15;
  const int quad = lane >> 4;
  const int wv   = t >> 6;
  const int wm   = wv & 1;
  const int wn   = wv >> 1;
  const int b    = blockIdx.x >> 3;
  const int n0   = (blockIdx.x & 7) << 7;
  const int o0   = blockIdx.y * BN;

  f32x4 acc[4][4];
#pragma unroll
  for (int i = 0; i < 4; ++i)
#pragma unroll
    for (int j = 0; j < 4; ++j)
#pragma unroll
      for (int k = 0; k < 4; ++k) acc[i][j][k] = 0.0f;

  // lane's slot = s4 + quad -> channels 2(s4+quad), 2(s4+quad)+1
  const float* Tp = T + (((size_t)(b * C_in + (quad << 1))) << 10) + n0 + (wm << 6) + col;
  const half8* Bp = wh + (size_t)blockIdx.y * nslot * BN + (size_t)quad * BN + wn * 64 + col;

  for (int s4 = 0; s4 < nslot; s4 += 4) {
    float t0[4], t1[4];
    half8 bf[4];
#pragma unroll
    for (int f = 0; f < 4; ++f) {
      t0[f] = Tp[f << 4];
      t1[f] = Tp[(f << 4) + 1024];
      bf[f] = Bp[f << 4];
    }
    Tp += (size_t)8 << 10;   // 8 channels = 4 slots
    Bp += (size_t)4 * BN;
    half8 af[4];
#pragma unroll
    for (int f = 0; f < 4; ++f) {
      float a = t0[f], c = t1[f];
      float as = a * a, cs = c * c;
      half8 h;
      h[0] = (_Float16)1.0f;
      h[1] = (_Float16)(a + a);
      h[2] = (_Float16)(3.75f * as - 0.75f);
      h[3] = (_Float16)(a * (7.0f * as - 3.0f));
      h[4] = (_Float16)1.0f;
      h[5] = (_Float16)(c + c);
      h[6] = (_Float16)(3.75f * cs - 0.75f);
      h[7] = (_Float16)(c * (7.0f * cs - 3.0f));
      af[f] = h;
    }
#pragma unroll
    for (int fm = 0; fm < 4; ++fm)
#pragma unroll
      for (int fn = 0; fn < 4; ++fn)
        acc[fm][fn] = __builtin_amdgcn_mfma_f32_16x16x32_f16(af[fm], bf[fn], acc[fm][fn], 0, 0, 0);
  }

  // ---- epilogue: unscale, bias, fp32 write, fused BN stats ----
  const float inv64 = 0.015625f;
#pragma unroll
  for (int fn = 0; fn < 4; ++fn) {
    const int cl = (wn << 6) + (fn << 4) + col;
    const int o  = o0 + cl;
    const float bb = bias ? bias[b * C_out + o] : 0.0f;
    float s = 0.f, s2 = 0.f, mx = -3.4e38f;
#pragma unroll
    for (int fm = 0; fm < 4; ++fm) {
      float v0 = acc[fm][fn][0] * inv64 + bb;
      float v1 = acc[fm][fn][1] * inv64 + bb;
      float v2 = acc[fm][fn][2] * inv64 + bb;
      float v3 = acc[fm][fn][3] * inv64 + bb;
      if (out) {
        *(float4*)(out + (((size_t)(b * C_out + o)) << 10) + n0 + (wm << 6) + (fm << 4) + (quad << 2)) =
            make_float4(v0, v1, v2, v3);
      }
      s  += v0 + v1 + v2 + v3;
      s2 += v0 * v0 + v1 * v1 + v2 * v2 + v3 * v3;
      mx  = fmaxf(fmaxf(v0, v1), fmaxf(fmaxf(v2, v3), mx));
    }
    s  += __shfl_down(s, 32);  s  += __shfl_down(s, 16);
    s2 += __shfl_down(s2, 32); s2 += __shfl_down(s2, 16);
    mx  = fmaxf(mx, __shfl_down(mx, 32)); mx = fmaxf(mx, __shfl_down(mx, 16));
    if (lane < 16) {
      sredS [cl][wm] = s;
      sredS2[cl][wm] = s2;
      sredM [cl][wm] = mx;
    }
  }
  __syncthreads();
  if (t < BN) {
    const int o = o0 + t;
    float s  = sredS [t][0] + sredS [t][1];
    float s2 = sredS2[t][0] + sredS2[t][1];
    if (out) {
      spart[(o << 8) + blockIdx.x] = make_float2(s, s2);
    } else {
      float mx = fmaxf(sredM[t][0], sredM[t][1]);
      atomicAdd(&stat_acc[o], s);
      atomicAdd(&stat_acc[C_out + o], s2);
      atomicMax(&max_acc[b * C_out + o], encf(mx));
    }
  }
}

// ---------- fp32 KAN layer (L1 only: C_in=2) ----------
template<int BM, int BN>
__global__ __launch_bounds__(256) void kan_gemm(
    const float*  __restrict__ in, const float2* __restrict__ stats,
    const float*  __restrict__ w, float* __restrict__ out,
    float2* __restrict__ spart, int C_in, int C_out)
{
  static_assert(BM * BN == 256 * 64, "8x8-per-thread tile requires BM*BN == 16384");
  constexpr int TM = BM / 8;
  constexpr int AE = 8 * BM / 256;
  constexpr int BE = 8 * BN / 256;
  __shared__ __align__(16) float As[32][BM];
  __shared__ __align__(16) float Bs[32][BN];

  const int t  = threadIdx.x;
  const int tpb = NPTS / BM;
  const int b  = blockIdx.x / tpb;
  const int n0 = (blockIdx.x % tpb) * BM;
  const int o0 = blockIdx.y * BN;
  const int tm = t % TM;
  const int to = t / TM;

  float acc[2][4][2][4];
#pragma unroll
  for (int a = 0; a < 2; ++a)
#pragma unroll
    for (int c = 0; c < 4; ++c)
#pragma unroll
      for (int d = 0; d < 2; ++d)
#pragma unroll
        for (int e = 0; e < 4; ++e) acc[a][c][d][e] = 0.0f;

  const int nch = (C_in + 7) >> 3;
  for (int ch = 0; ch < nch; ++ch) {
    const int i0 = ch << 3;
    __syncthreads();
#pragma unroll
    for (int r = 0; r < AE; ++r) {
      int e  = t + (r << 8);
      int il = e / BM, n = e % BM;
      int i  = i0 + il;
      float p0 = 0.f, p1 = 0.f, p2 = 0.f, p3 = 0.f;
      if (i < C_in) {
        float v = in[((size_t)(b * C_in + i) << 10) + n0 + n];
        if (stats) { float2 s = stats[i]; v = (v - s.x) * s.y; }
        jacobi4(fast_tanh(v), p0, p1, p2, p3);
      }
      As[(il << 2) + 0][n] = p0;
      As[(il << 2) + 1][n] = p1;
      As[(il << 2) + 2][n] = p2;
      As[(il << 2) + 3][n] = p3;
    }
#pragma unroll
    for (int r = 0; r < BE; ++r) {
      int e  = t + (r << 8);
      int il = e / BN, o = e % BN;
      int i  = i0 + il;
      float4 wv = make_float4(0.f, 0.f, 0.f, 0.f);
      if (i < C_in) wv = *(const float4*)(w + (((size_t)i * C_out + o0 + o) << 2));
      Bs[(il << 2) + 0][o] = wv.x;
      Bs[(il << 2) + 1][o] = wv.y;
      Bs[(il << 2) + 2][o] = wv.z;
      Bs[(il << 2) + 3][o] = wv.w;
    }
    __syncthreads();
#pragma unroll 8
    for (int k = 0; k < 32; ++k) {
      const float4 a0 = *(const float4*)&As[k][tm << 2];
      const float4 a1 = *(const float4*)&As[k][(BM / 2) + (tm << 2)];
      const float4 b0 = *(const float4*)&Bs[k][to << 2];
      const float4 b1 = *(const float4*)&Bs[k][(BN / 2) + (to << 2)];
      const float am[2][4] = {{a0.x, a0.y, a0.z, a0.w}, {a1.x, a1.y, a1.z, a1.w}};
      const float bo[2][4] = {{b0.x, b0.y, b0.z, b0.w}, {b1.x, b1.y, b1.z, b1.w}};
#pragma unroll
      for (int oh = 0; oh < 2; ++oh)
#pragma unroll
        for (int oj = 0; oj < 4; ++oj) {
          const float bv = bo[oh][oj];
#pragma unroll
          for (int mh = 0; mh < 2; ++mh)
#pragma unroll
            for (int mj = 0; mj < 4; ++mj)
              acc[oh][oj][mh][mj] = fmaf(bv, am[mh][mj], acc[oh][oj][mh][mj]);
        }
    }
  }

#pragma unroll
  for (int oh = 0; oh < 2; ++oh)
#pragma unroll
    for (int oj = 0; oj < 4; ++oj) {
      const int o = o0 + oh * (BN / 2) + (to << 2) + oj;
      float s = 0.f, s2 = 0.f;
#pragma unroll
      for (int mh = 0; mh < 2; ++mh) {
        float4 v = make_float4(acc[oh][oj][mh][0], acc[oh][oj][mh][1],
                               acc[oh][oj][mh][2], acc[oh][oj][mh][3]);
        *(float4*)(out + (((size_t)(b * C_out + o)) << 10) + n0 + mh * (BM / 2) + (tm << 2)) = v;
        s  += v.x + v.y + v.z + v.w;
        s2 += v.x * v.x + v.y * v.y + v.z * v.z + v.w * v.w;
      }
#pragma unroll
      for (int off = TM / 2; off > 0; off >>= 1) {
        s  += __shfl_down(s, off, TM);
        s2 += __shfl_down(s2, off, TM);
      }
      if (tm == 0) spart[(o << 8) + blockIdx.x] = make_float2(s, s2);
    }
}

// ---------- reduce per-block partials -> BN stats ----------
__global__ __launch_bounds__(256) void bn_finalize2(
    const float2* __restrict__ spart, float2* __restrict__ stats, int C, int nxb)
{
  int c = blockIdx.x, t = threadIdx.x;
  float s = 0.f, s2 = 0.f;
  if (t < nxb) { float2 p = spart[(c << 8) + t]; s = p.x; s2 = p.y; }
#pragma unroll
  for (int off = 32; off > 0; off >>= 1) {
    s  += __shfl_down(s, off);
    s2 += __shfl_down(s2, off);
  }
  __shared__ float rs[4], rs2[4];
  int wid = t >> 6;
  if ((t & 63) == 0) { rs[wid] = s; rs2[wid] = s2; }
  __syncthreads();
  if (t == 0) {
    s  = rs[0] + rs[1] + rs[2] + rs[3];
    s2 = rs2[0] + rs2[1] + rs2[2] + rs2[3];
    float m   = s * (1.0f / NTOT);
    float var = s2 * (1.0f / NTOT) - m * m;
    stats[c] = make_float2(m, rsqrtf(var + 1e-5f));
  }
}

// ---------- finalize layer-5 stats from atomic accumulators ----------
__global__ void bn_finalize(const float* __restrict__ stat_acc,
                            float2* __restrict__ stats, int C) {
  int c = blockIdx.x * 256 + threadIdx.x;
  if (c < C) {
    float m   = stat_acc[c] * (1.0f / NTOT);
    float var = stat_acc[C + c] * (1.0f / NTOT) - m * m;
    stats[c] = make_float2(m, rsqrtf(var + 1e-5f));
  }
}

// ---------- global-feature branch of layer 6, parallel ----------
__global__ __launch_bounds__(256) void pool_const6p(
    const unsigned* __restrict__ max_acc, const float2* __restrict__ stats5,
    const float* __restrict__ w6, float* __restrict__ cst)
{
  __shared__ __align__(16) float4 P[32][64];
  const int t  = threadIdx.x;
  const int ot = blockIdx.x;
  const int c0 = blockIdx.y << 6;
#pragma unroll
  for (int it = 0; it < 8; ++it) {
    int idx = t + (it << 8);
    int b = idx >> 6, cl = idx & 63;
    int c = c0 + cl;
    float mx = decf(max_acc[(b << 10) + c]);
    float2 s = stats5[c];
    float tt = fast_tanh((mx - s.x) * s.y);
    float p0, p1, p2, p3; jacobi4(tt, p0, p1, p2, p3);
    P[b][cl] = make_float4(p0, p1, p2, p3);
  }
  __syncthreads();
  const int oL = t & 63;
  const int bg = t >> 6;
  const int o  = (ot << 6) + oL;
  float acc[8];
#pragma unroll
  for (int i = 0; i < 8; ++i) acc[i] = 0.f;
  for (int cl = 0; cl < 64; ++cl) {
    const float4 wv = *(const float4*)(w6 + (((size_t)(64 + c0 + cl) * 512 + o) << 2));
#pragma unroll
    for (int bb = 0; bb < 8; ++bb) {
      float4 p = P[(bg << 3) + bb][cl];
      acc[bb] += p.x * wv.x + p.y * wv.y + p.z * wv.z + p.w * wv.w;
    }
  }
#pragma unroll
  for (int bb = 0; bb < 8; ++bb)
    atomicAdd(&cst[(((bg << 3) + bb) << 9) + o], acc[bb]);
}

// ---------- final layer: C_in=128 fp32 -> C_out=3 fp32 ----------
__global__ __launch_bounds__(256) void kan_final(
    const float* __restrict__ in, const float2* __restrict__ stats,
    const float* __restrict__ w, float* __restrict__ out)
{
  int g = blockIdx.x * 256 + threadIdx.x;
  int b = g >> 10, n = g & 1023;
  float a0 = 0.f, a1 = 0.f, a2 = 0.f;
  for (int i = 0; i < 128; ++i) {
    float v = in[((size_t)(b * 128 + i) << 10) + n];
    float2 s = stats[i];
    float p0, p1, p2, p3; jacobi4(fast_tanh((v - s.x) * s.y), p0, p1, p2, p3);
    const float4 w0 = *(const float4*)(w + ((i * 3 + 0) << 2));
    const float4 w1 = *(const float4*)(w + ((i * 3 + 1) << 2));
    const float4 w2 = *(const float4*)(w + ((i * 3 + 2) << 2));
    a0 += p0 * w0.x + p1 * w0.y + p2 * w0.z + p3 * w0.w;
    a1 += p0 * w1.x + p1 * w1.y + p2 * w1.z + p3 * w1.w;
    a2 += p0 * w2.x + p1 * w2.y + p2 * w2.z + p3 * w2.w;
  }
  out[((b * 3 + 0) << 10) + n] = a0;
  out[((b * 3 + 1) << 10) + n] = a1;
  out[((b * 3 + 2) << 10) + n] = a2;
}

// ---------- launch ----------
extern "C" void kernel_launch(void* const* d_in, const int* in_sizes, int n_in,
                              void* d_out, int out_size, void* d_ws, size_t ws_size,
                              hipStream_t stream) {
  const float* x   = (const float*)d_in[0];
  const float* w1  = (const float*)d_in[1];
  const float* w2  = (const float*)d_in[2];
  const float* w3  = (const float*)d_in[3];
  const float* w4  = (const float*)d_in[4];
  const float* w5  = (const float*)d_in[5];
  const float* w6  = (const float*)d_in[6];
  const float* w7  = (const float*)d_in[7];
  const float* w8  = (const float*)d_in[8];
  const float* w9  = (const float*)d_in[9];
  const float* w10 = (const float*)d_in[10];

  float* ws = (float*)d_ws;
  // misc region (floats)
  float*    stat_acc = ws + 0;                      // 2048
  unsigned* maxenc   = (unsigned*)(ws + 2048);      // 32768
  float*    cst6     = ws + 34816;                  // 16384 (zeroed)
  float2*   spart    = (float2*)(ws + 51200);       // 131072 float2 -> ends 313344
  float2*   stats1   = (float2*)(ws + 313344);
  float2*   stats2   = stats1 + 64;
  float2*   stats3   = stats2 + 64;
  float2*   stats4   = stats3 + 64;
  float2*   stats5   = stats4 + 128;
  float2*   stats6   = stats5 + 1024;
  float2*   stats7   = stats6 + 512;
  float2*   stats8   = stats7 + 256;
  float2*   stats9   = stats8 + 128;
  // fp16 weight pool (half8 units) @ float offset 318464
  half8*    whbase = (half8*)(ws + 318464);
  half8*    h2 = whbase + 0;        // 32*64    = 2048
  half8*    h3 = whbase + 2048;     // 2048
  half8*    h4 = whbase + 4096;     // 32*128   = 4096
  half8*    h5 = whbase + 8192;     // 64*1024  = 65536
  half8*    h6 = whbase + 73728;    // 32*512   = 16384
  half8*    h7 = whbase + 90112;    // 256*256  = 65536
  half8*    h8 = whbase + 155648;   // 128*128  = 16384
  half8*    h9 = whbase + 172032;   // 64*128   = 8192  -> ends 180224 h8 = 720896 fl
  // data pool (fp32 y; act converts y -> t IN PLACE). Liveness-based aliasing:
  //   P+0        .. +2M   : y2/T2        (live L2..L6)
  //   P+2M       .. +18.8M: y6/T6        (live L6..L7) — region reused before L6 by:
  //       P+2M  .. +4M    : y1/T1        (dead after L2)
  //       P+4M  .. +6M    : y3/T3        (dead after L4)
  //       P+6M  .. +10M   : y4/T4        (dead after L5)
  //     and after L7 by:
  //       P+2M  .. +6M    : y8/T8        (live L8..L9)
  //       P+6M  .. +10M   : y9           (live L9..L10)
  //   P+18.8M    .. +27.2M: y7/T7        (live L7..L8)
  float* P   = ws + 1048576;
  float* yT2 = P;
  float* y6  = P + 2097152;
  float* y1  = P + 2097152;
  float* y3  = P + 4194304;
  float* y4  = P + 6291456;
  float* y8  = P + 2097152;
  float* y9  = P + 6291456;
  float* y7  = P + 18874368;
  // total: 1048576 + 27262976 floats = ~113 MB

  dim3 blk(256);
  zero_ws<<<200, blk, 0, stream>>>((unsigned*)ws, 51200);
  // preconvert weights
  conv_w16<<<8,   blk, 0, stream>>>(w2, h2, 64, 64, 64);
  conv_w16<<<8,   blk, 0, stream>>>(w3, h3, 64, 64, 64);
  conv_w16<<<16,  blk, 0, stream>>>(w4, h4, 64, 128, 128);
  conv_w16<<<256, blk, 0, stream>>>(w5, h5, 128, 1024, 128);
  conv_w16<<<64,  blk, 0, stream>>>(w6, h6, 64, 512, 128);   // local rows 0..63
  conv_w16<<<256, blk, 0, stream>>>(w7, h7, 512, 256, 128);
  conv_w16<<<64,  blk, 0, stream>>>(w8, h8, 256, 128, 128);
  conv_w16<<<32,  blk, 0, stream>>>(w9, h9, 128, 128, 128);

  // L1: 2 -> 64 fp32
  kan_gemm<256, 64><<<dim3(128, 1), blk, 0, stream>>>(x, nullptr, w1, y1, spart, 2, 64);
  bn_finalize2<<<64, blk, 0, stream>>>(spart, stats1, 64, 128);
  act_tanh<<<32 * 64, blk, 0, stream>>>(y1, stats1, 64);                       // T1
  // L2: 64 -> 64
  kan_mfma3<1><<<dim3(256, 1), 128, 0, stream>>>(y1, h2, nullptr, yT2, spart, nullptr, nullptr, 64, 64);
  bn_finalize2<<<64, blk, 0, stream>>>(spart, stats2, 64, 256);
  act_tanh<<<32 * 64, blk, 0, stream>>>(yT2, stats2, 64);                      // T2 (kept for L6)
  // L3: 64 -> 64
  kan_mfma3<1><<<dim3(256, 1), 128, 0, stream>>>(yT2, h3, nullptr, y3, spart, nullptr, nullptr, 64, 64);
  bn_finalize2<<<64, blk, 0, stream>>>(spart, stats3, 64, 256);
  act_tanh<<<32 * 64, blk, 0, stream>>>(y3, stats3, 64);                       // T3
  // L4: 64 -> 128
  kan_mfma3<2><<<dim3(256, 1), blk, 0, stream>>>(y3, h4, nullptr, y4, spart, nullptr, nullptr, 64, 128);
  bn_finalize2<<<128, blk, 0, stream>>>(spart, stats4, 128, 256);
  act_tanh<<<32 * 128, blk, 0, stream>>>(y4, stats4, 128);                     // T4
  // L5: 128 -> 1024, fused stats + maxpool, no materialization
  kan_mfma3<2><<<dim3(256, 8), blk, 0, stream>>>(y4, h5, nullptr, nullptr, nullptr, stat_acc, maxenc, 128, 1024);
  bn_finalize<<<4, blk, 0, stream>>>(stat_acc, stats5, 1024);
  // gf branch of layer 6
  pool_const6p<<<dim3(8, 16), blk, 0, stream>>>(maxenc, stats5, w6, cst6);
  // L6: 64 (local, T2) -> 512 + gf bias
  kan_mfma3<2><<<dim3(256, 4), blk, 0, stream>>>(yT2, h6, cst6, y6, spart, nullptr, nullptr, 64, 512);
  bn_finalize2<<<512, blk, 0, stream>>>(spart, stats6, 512, 256);
  act_tanh<<<32 * 512, blk, 0, stream>>>(y6, stats6, 512);                     // T6
  // L7: 512 -> 256
  kan_mfma3<2><<<dim3(256, 2), blk, 0, stream>>>(y6, h7, nullptr, y7, spart, nullptr, nullptr, 512, 256);
  bn_finalize2<<<256, blk, 0, stream>>>(spart, stats7, 256, 256);
  act_tanh<<<32 * 256, blk, 0, stream>>>(y7, stats7, 256);                     // T7
  // L8: 256 -> 128
  kan_mfma3<2><<<dim3(256, 1), blk, 0, stream>>>(y7, h8, nullptr, y8, spart, nullptr, nullptr, 256, 128);
  bn_finalize2<<<128, blk, 0, stream>>>(spart, stats8, 128, 256);
  act_tanh<<<32 * 128, blk, 0, stream>>>(y8, stats8, 128);                     // T8
  // L9: 128 -> 128
  kan_mfma3<2><<<dim3(256, 1), blk, 0, stream>>>(y8, h9, nullptr, y9, spart, nullptr, nullptr, 128, 128);
  bn_finalize2<<<128, blk, 0, stream>>>(spart, stats9, 128, 256);
  // L10: 128 -> 3 (tanh+Jacobi inline, fp32)
  kan_final<<<128, blk, 0, stream>>>(y9, stats9, w10, (float*)d_out);
}